// Round 3
// baseline (229.953 us; speedup 1.0000x reference)
//
#include <hip/hip_runtime.h>
#include <stdint.h>

// hetero_effect_graph: 2-layer RGCN over dense level-partitioned bipartite graph.
//  k_prep : transpose+bf16 root1,root2,W1[1..5],W2[1..5]
//  k_lev  : sel = ceil(w*6) in 0..6, 4-bit packed k-major (levq[k/8][row] u32,
//           coalesced via LDS tile transpose), relation counts -> inv, xe->bf16, out := b1
//  k_gemm : m1 = relu(xm@root1+b1); zpk[r] = (A@W[r]) packed k-major [r][k/8][d][8]
//           with k-order [0,2,4,6,1,3,5,7] inside each 8-chunk (matches nibble unpack)
//  k_conv : out += sum_r (inv_r*mask_r) @ Z_r via MFMA; A fragments via v_perm_b32
//           byte tables; KSPLIT=16 for occupancy; + root k-slice on ks<8; f32 atomics.
//  k_fin  : e1 = relu(out) -> bf16 (reuses xebf buf), out := b2

#define NE 10000
#define NM 2048
#define NEPAD 10112   // 79 * 128
#define MTILES 79
#define KSPLIT 16

typedef short bf8_t __attribute__((ext_vector_type(8)));
typedef float f16f  __attribute__((ext_vector_type(16)));

__device__ __forceinline__ uint16_t f2bf(float f){
  uint32_t u = __float_as_uint(f);
  u += 0x7FFFu + ((u >> 16) & 1u);
  return (uint16_t)(u >> 16);
}

__device__ __forceinline__ f16f mfma32(bf8_t a, bf8_t b, f16f c){
  return __builtin_amdgcn_mfma_f32_32x32x16_bf16(a, b, c, 0, 0, 0);
}

// ---- transpose + bf16 convert the small weight matrices ----
__global__ __launch_bounds__(256) void k_prep(
    const float* __restrict__ root1, const float* __restrict__ root2,
    const float* __restrict__ W1, const float* __restrict__ W2,
    uint16_t* __restrict__ r1t, uint16_t* __restrict__ r2t,
    uint16_t* __restrict__ w1t, uint16_t* __restrict__ w2t){
  int idx = blockIdx.x*256 + threadIdx.x;
  int slab = idx >> 14;
  int pos  = idx & 16383;
  int d = pos >> 7, k = pos & 127;
  float v; uint16_t* dst;
  if (slab == 0)      { v = root1[k*128 + d]; dst = r1t; }
  else if (slab == 1) { v = root2[k*128 + d]; dst = r2t; }
  else if (slab < 7)  { v = W1[(slab-1)*16384 + k*128 + d]; dst = w1t + (slab-2)*16384; }
  else                { v = W2[(slab-6)*16384 + k*128 + d]; dst = w2t + (slab-7)*16384; }
  dst[pos] = f2bf(v);
}

// ---- 32 rows/block: levq (4-bit, k-major, coalesced), inv, xe->bf16, out := b1 ----
__global__ __launch_bounds__(256) void k_lev(
    const float* __restrict__ w, const float* __restrict__ xe,
    const float* __restrict__ b1, uint32_t* __restrict__ levq,
    float* __restrict__ inv, uint16_t* __restrict__ xebf,
    float* __restrict__ out){
  int t = threadIdx.x;
  int brow = blockIdx.x * 32;
  int rloc = t >> 3, p = t & 7;          // 8 threads per row
  int row = brow + rloc;
  bool active = row < NE;
  const float* wr = w + (size_t)row * NM;
  unsigned long long cnt = 0ull;         // 5 x 12-bit packed relation counters
  __shared__ uint32_t tile[32][33];

  for (int cp = 0; cp < 8; cp++){        // 8 column-panels of 256 cols
    uint32_t packs[4];
    #pragma unroll
    for (int q = 0; q < 4; q++){
      int gck = cp*32 + p + 8*q;         // global 8-col chunk
      uint32_t L = 0;
      if (active){
        const float4* f = (const float4*)(wr + gck*8);
        float4 f0 = f[0], f1 = f[1];
        float wv[8] = {f0.x,f0.y,f0.z,f0.w, f1.x,f1.y,f1.z,f1.w};
        #pragma unroll
        for (int e = 0; e < 8; e++){
          int s = (int)ceilf(wv[e]*6.0f);          // lev+1 in 1..6
          if (s >= 2) cnt += 1ull << (12*(s-2));   // relations 1..5
          L |= (uint32_t)s << (4*e);               // nibble e = entry e
        }
      }
      packs[q] = L;
    }
    __syncthreads();
    #pragma unroll
    for (int q = 0; q < 4; q++) tile[p + 8*q][rloc] = packs[q];
    __syncthreads();
    // coalesced writeout: thread t -> chunk t>>3, 4 consecutive rows (uint4)
    int ckk = t >> 3;
    int r4  = (t & 7) * 4;
    size_t base = (size_t)(cp*32 + ckk) * NEPAD + brow + r4;
    *(uint4*)(levq + base) = make_uint4(tile[ckk][r4], tile[ckk][r4+1],
                                        tile[ckk][r4+2], tile[ckk][r4+3]);
  }

  // reduce packed counters across the 8 threads of each row
  unsigned long long c = cnt;
  c += __shfl_xor(c, 1);
  c += __shfl_xor(c, 2);
  c += __shfl_xor(c, 4);
  if (p == 0 && row < NEPAD){
    if (active){
      inv[row*8 + 0] = 0.f; inv[row*8 + 6] = 0.f; inv[row*8 + 7] = 0.f;
      #pragma unroll
      for (int r = 1; r <= 5; r++){
        uint32_t cc = (uint32_t)((c >> (12*(r-1))) & 0xFFFull);
        inv[row*8 + r] = cc ? 1.0f/(float)cc : 0.f;
      }
    } else {
      #pragma unroll
      for (int i = 0; i < 8; i++) inv[row*8 + i] = 0.f;
    }
  }

  // xe -> bf16 (+ zero pads), out := b1
  int f0i = p * 16;
  if (active){
    union { uint16_t u[16]; uint4 q[2]; } ub;
    #pragma unroll
    for (int j = 0; j < 4; j++){
      float4 a = *(const float4*)(xe + (size_t)row*128 + f0i + j*4);
      ub.u[j*4+0]=f2bf(a.x); ub.u[j*4+1]=f2bf(a.y); ub.u[j*4+2]=f2bf(a.z); ub.u[j*4+3]=f2bf(a.w);
      *(float4*)(out + (size_t)row*128 + f0i + j*4) = *(const float4*)(b1 + f0i + j*4);
    }
    *(uint4*)(xebf + (size_t)row*128 + f0i)     = ub.q[0];
    *(uint4*)(xebf + (size_t)row*128 + f0i + 8) = ub.q[1];
  } else if (row < NEPAD){
    uint4 z = make_uint4(0,0,0,0);
    *(uint4*)(xebf + (size_t)row*128 + f0i)     = z;
    *(uint4*)(xebf + (size_t)row*128 + f0i + 8) = z;
  }
}

// ---- small GEMM [2048x128]@[128x128]; epilogue: m1 (bias+relu) or zpk pack ----
// zpk pack k-order within chunk: local k j -> pos = (j&1)*4 + (j>>1)
template<bool ABF16>
__global__ __launch_bounds__(256) void k_gemm(
    const float* __restrict__ Af, const uint16_t* __restrict__ Ab,
    const uint16_t* __restrict__ Bm, const uint16_t* __restrict__ Bz,
    const float* __restrict__ bias, uint16_t* __restrict__ m1out,
    uint16_t* __restrict__ zpk){
  int tid = threadIdx.x;
  int lane = tid & 63, wid = tid >> 6;
  int l31 = lane & 31, g = lane >> 5;
  int by = blockIdx.y;
  bool m1path = (Bm != nullptr) && (by == 0);
  int r = (Bm != nullptr) ? by - 1 : by;
  const uint16_t* B = m1path ? Bm : (Bz + (size_t)r*16384);
  int arow = blockIdx.x*128 + wid*32 + l31;

  f16f acc[4];
  #pragma unroll
  for (int n = 0; n < 4; n++)
    #pragma unroll
    for (int i = 0; i < 16; i++) acc[n][i] = 0.f;

  #pragma unroll
  for (int ksI = 0; ksI < 8; ksI++){
    int k0 = ksI*16 + g*8;
    bf8_t a;
    if (ABF16){
      a = *(const bf8_t*)(Ab + (size_t)arow*128 + k0);
    } else {
      const float* ap = Af + (size_t)arow*128 + k0;
      float4 f0 = *(const float4*)ap;
      float4 f1 = *(const float4*)(ap + 4);
      union { uint16_t u[8]; bf8_t v; } ua;
      ua.u[0]=f2bf(f0.x); ua.u[1]=f2bf(f0.y); ua.u[2]=f2bf(f0.z); ua.u[3]=f2bf(f0.w);
      ua.u[4]=f2bf(f1.x); ua.u[5]=f2bf(f1.y); ua.u[6]=f2bf(f1.z); ua.u[7]=f2bf(f1.w);
      a = ua.v;
    }
    #pragma unroll
    for (int n = 0; n < 4; n++){
      bf8_t b = *(const bf8_t*)(B + (size_t)(n*32 + l31)*128 + k0);
      acc[n] = mfma32(a, b, acc[n]);
    }
  }
  #pragma unroll
  for (int n = 0; n < 4; n++){
    int colg = n*32 + l31;
    float bv = m1path ? bias[colg] : 0.f;
    #pragma unroll
    for (int v = 0; v < 16; v++){
      int rowl = (v&3) + 8*(v>>2) + 4*g;
      int rg = blockIdx.x*128 + wid*32 + rowl;   // mole index j
      float val = acc[n][v];
      if (m1path){
        m1out[(size_t)rg*128 + colg] = f2bf(fmaxf(val + bv, 0.f));
      } else {
        int pos = ((rg & 1) << 2) | ((rg & 7) >> 1);
        zpk[(size_t)(r*256 + (rg>>3))*1024 + colg*8 + pos] = f2bf(val);
      }
    }
  }
}

// ---- masked RGCN conv with perm-built A fragments (KSPLIT=16) ----
__global__ __launch_bounds__(256, 2) void k_conv(
    const uint32_t* __restrict__ levq, const float* __restrict__ inv,
    const uint16_t* __restrict__ zpk, const uint16_t* __restrict__ aroot,
    const uint16_t* __restrict__ rt, float* __restrict__ tgt){
  int tid = threadIdx.x;
  int lane = tid & 63, wid = tid >> 6;
  int wm = wid >> 1, wn = wid & 1;
  int l31 = lane & 31, g = lane >> 5;
  int brow = blockIdx.x*128;
  int ks = blockIdx.y;

  int rg0 = brow + 64*wm + l31;
  int rg1 = rg0 + 32;

  // per-relation byte tables: byte (r+1) of the 8-byte pool = inv_r's lo/hi byte
  uint32_t tlo[2][5], thi[2][5];
  #pragma unroll
  for (int mt = 0; mt < 2; mt++){
    int rg = mt ? rg1 : rg0;
    #pragma unroll
    for (int r = 1; r <= 5; r++){
      uint32_t bits = (uint32_t)f2bf(inv[(size_t)rg*8 + r]);
      int sh = 8*((r+1)&3);
      tlo[mt][r-1] = (bits & 0xFFu) << sh;
      thi[mt][r-1] = (bits >> 8)    << sh;
    }
  }

  f16f acc[2][2];
  #pragma unroll
  for (int a0=0;a0<2;a0++)
    #pragma unroll
    for (int b0=0;b0<2;b0++)
      #pragma unroll
      for (int i=0;i<16;i++) acc[a0][b0][i]=0.f;

  int kb = ks*16 + g;   // base 8-k chunk for this lane group
  const uint16_t* zr0 = zpk + (size_t)(64*wn      + l31)*8;
  const uint16_t* zr1 = zpk + (size_t)(64*wn + 32 + l31)*8;

  #pragma unroll 2
  for (int kk = 0; kk < 8; kk++){
    int kt = kb + kk*2;
    uint32_t L0 = levq[(size_t)kt*NEPAD + rg0];
    uint32_t L1 = levq[(size_t)kt*NEPAD + rg1];
    uint32_t sx0 = L0 & 0x0F0F0F0Fu, sy0 = (L0 >> 4) & 0x0F0F0F0Fu;
    uint32_t sx1 = L1 & 0x0F0F0F0Fu, sy1 = (L1 >> 4) & 0x0F0F0F0Fu;
    #pragma unroll
    for (int r = 1; r <= 5; r++){
      size_t zb = (size_t)((r-1)*256 + kt) * 1024;
      bf8_t bn0 = *(const bf8_t*)(zr0 + zb);
      bf8_t bn1 = *(const bf8_t*)(zr1 + zb);
      #pragma unroll
      for (int mt = 0; mt < 2; mt++){
        uint32_t sx = mt ? sx1 : sx0;
        uint32_t sy = mt ? sy1 : sy0;
        uint32_t TL = tlo[mt][r-1], TH = thi[mt][r-1];
        uint32_t pl0, ph0, pl1, ph1;
        if (r < 3){   // table byte at index 2..3 -> low pool (src1)
          pl0 = __builtin_amdgcn_perm(0u, TL, sx);
          ph0 = __builtin_amdgcn_perm(0u, TH, sx);
          pl1 = __builtin_amdgcn_perm(0u, TL, sy);
          ph1 = __builtin_amdgcn_perm(0u, TH, sy);
        } else {      // table byte at index 4..6 -> high pool (src0)
          pl0 = __builtin_amdgcn_perm(TL, 0u, sx);
          ph0 = __builtin_amdgcn_perm(TH, 0u, sx);
          pl1 = __builtin_amdgcn_perm(TL, 0u, sy);
          ph1 = __builtin_amdgcn_perm(TH, 0u, sy);
        }
        union { uint32_t u[4]; bf8_t v; } A;
        A.u[0] = __builtin_amdgcn_perm(ph0, pl0, 0x05010400u);
        A.u[1] = __builtin_amdgcn_perm(ph0, pl0, 0x07030602u);
        A.u[2] = __builtin_amdgcn_perm(ph1, pl1, 0x05010400u);
        A.u[3] = __builtin_amdgcn_perm(ph1, pl1, 0x07030602u);
        acc[mt][0] = mfma32(A.v, bn0, acc[mt][0]);
        acc[mt][1] = mfma32(A.v, bn1, acc[mt][1]);
      }
    }
  }

  if (ks < 8){   // this block's root-matmul k-slice (balanced across first 8 ks)
    int k0 = ks*16 + g*8;
    bf8_t a0  = *(const bf8_t*)(aroot + (size_t)rg0*128 + k0);
    bf8_t a1  = *(const bf8_t*)(aroot + (size_t)rg1*128 + k0);
    bf8_t rb0 = *(const bf8_t*)(rt + (size_t)(64*wn      + l31)*128 + k0);
    bf8_t rb1 = *(const bf8_t*)(rt + (size_t)(64*wn + 32 + l31)*128 + k0);
    acc[0][0] = mfma32(a0, rb0, acc[0][0]);
    acc[0][1] = mfma32(a0, rb1, acc[0][1]);
    acc[1][0] = mfma32(a1, rb0, acc[1][0]);
    acc[1][1] = mfma32(a1, rb1, acc[1][1]);
  }

  #pragma unroll
  for (int mt = 0; mt < 2; mt++){
    #pragma unroll
    for (int nt = 0; nt < 2; nt++){
      int colg = 64*wn + 32*nt + l31;
      #pragma unroll
      for (int v = 0; v < 16; v++){
        int rowl = (v&3) + 8*(v>>2) + 4*g;
        int rg = brow + 64*wm + 32*mt + rowl;
        if (rg < NE) unsafeAtomicAdd(&tgt[(size_t)rg*128 + colg], acc[mt][nt][v]);
      }
    }
  }
}

// ---- e1 = relu(out) -> bf16 (into xebf buffer); out := b2 ----
__global__ __launch_bounds__(256) void k_fin(
    float* __restrict__ dout, const float* __restrict__ b2,
    uint16_t* __restrict__ e1bf){
  int idx4 = (blockIdx.x*256 + threadIdx.x) * 4;
  float4 v = *(const float4*)(dout + idx4);
  union { uint16_t u[4]; uint2 q; } ub;
  ub.u[0] = f2bf(fmaxf(v.x, 0.f));
  ub.u[1] = f2bf(fmaxf(v.y, 0.f));
  ub.u[2] = f2bf(fmaxf(v.z, 0.f));
  ub.u[3] = f2bf(fmaxf(v.w, 0.f));
  *(uint2*)(e1bf + idx4) = ub.q;
  *(float4*)(dout + idx4) = *(const float4*)(b2 + (idx4 & 127));
}

extern "C" void kernel_launch(void* const* d_in, const int* in_sizes, int n_in,
                              void* d_out, int out_size, void* d_ws, size_t ws_size,
                              hipStream_t stream){
  const float* xe  = (const float*)d_in[0];
  const float* xm  = (const float*)d_in[1];
  const float* w   = (const float*)d_in[2];
  const float* W1  = (const float*)d_in[3];
  const float* r1  = (const float*)d_in[4];
  const float* b1  = (const float*)d_in[5];
  const float* W2  = (const float*)d_in[6];
  const float* r2  = (const float*)d_in[7];
  const float* b2  = (const float*)d_in[8];
  float* out = (float*)d_out;
  char* ws = (char*)d_ws;

  constexpr size_t OFF_INV  = 0;                                   // NEPAD*8*4
  constexpr size_t OFF_XEBF = OFF_INV  + (size_t)NEPAD*8*4;        // NEPAD*128*2 (also e1bf)
  constexpr size_t OFF_M1   = OFF_XEBF + (size_t)NEPAD*128*2;      // NM*128*2
  constexpr size_t OFF_Z1   = OFF_M1   + (size_t)NM*128*2;         // 5*NM*128*2
  constexpr size_t OFF_Z2   = OFF_Z1   + (size_t)5*NM*128*2;       // 5*NM*128*2
  constexpr size_t OFF_R1T  = OFF_Z2   + (size_t)5*NM*128*2;
  constexpr size_t OFF_R2T  = OFF_R1T  + 128*128*2;
  constexpr size_t OFF_W1T  = OFF_R2T  + 128*128*2;
  constexpr size_t OFF_W2T  = OFF_W1T  + (size_t)5*128*128*2;
  constexpr size_t OFF_LEVQ = OFF_W2T  + (size_t)5*128*128*2;      // 256*NEPAD*4 (~10.4MB)

  float*    inv  = (float*)   (ws + OFF_INV);
  uint16_t* xebf = (uint16_t*)(ws + OFF_XEBF);
  uint16_t* m1   = (uint16_t*)(ws + OFF_M1);
  uint16_t* z1   = (uint16_t*)(ws + OFF_Z1);
  uint16_t* z2   = (uint16_t*)(ws + OFF_Z2);
  uint16_t* r1t  = (uint16_t*)(ws + OFF_R1T);
  uint16_t* r2t  = (uint16_t*)(ws + OFF_R2T);
  uint16_t* w1t  = (uint16_t*)(ws + OFF_W1T);
  uint16_t* w2t  = (uint16_t*)(ws + OFF_W2T);
  uint32_t* levq = (uint32_t*)(ws + OFF_LEVQ);

  hipLaunchKernelGGL(k_prep, dim3(768), dim3(256), 0, stream,
                     r1, r2, W1, W2, r1t, r2t, w1t, w2t);
  hipLaunchKernelGGL(k_lev, dim3(NEPAD/32), dim3(256), 0, stream,
                     w, xe, b1, levq, inv, xebf, out);
  // y=0: m1 = relu(xm@root1+b1); y=1..5: z1[y-1] = pack(xm@W1[y-1])
  hipLaunchKernelGGL((k_gemm<false>), dim3(16,6), dim3(256), 0, stream,
                     xm, (const uint16_t*)nullptr, r1t, w1t, b1, m1, z1);
  // z2[r] = pack(m1@W2[r])  (independent of conv1; fills pipeline)
  hipLaunchKernelGGL((k_gemm<true>), dim3(16,5), dim3(256), 0, stream,
                     (const float*)nullptr, m1, (const uint16_t*)nullptr, w2t,
                     (const float*)nullptr, (uint16_t*)nullptr, z2);
  // conv1 -> out (pre-initialized with b1)
  hipLaunchKernelGGL(k_conv, dim3(MTILES, KSPLIT), dim3(256), 0, stream,
                     levq, inv, z1, xebf, r1t, out);
  // e1 = relu(out) -> xebf buffer ; out := b2
  hipLaunchKernelGGL(k_fin, dim3(NE*128/1024), dim3(256), 0, stream, out, b2, xebf);
  // conv2 -> out
  hipLaunchKernelGGL(k_conv, dim3(MTILES, KSPLIT), dim3(256), 0, stream,
                     levq, inv, z2, xebf, r2t, out);
}

// Round 4
// 180.677 us; speedup vs baseline: 1.2727x; 1.2727x over previous
//
#include <hip/hip_runtime.h>
#include <stdint.h>

// hetero_effect_graph: 2-layer RGCN over dense level-partitioned bipartite graph.
//  k_prep : transpose+bf16 root1,root2,W1[1..5],W2[1..5]
//  k_lev  : sel = ceil(w*6) in 0..6, 4-bit packed k-major (levq[k/8][row] u32,
//           coalesced via LDS tile transpose), relation counts -> inv, xe->bf16
//  k_gemm : m1 = relu(xm@root1+b1); z[r] = (A@W[r]) packed k-major [r][k/8][d][8]
//           with k-order [0,2,4,6,1,3,5,7] inside each 8-chunk (matches nibble unpack)
//  k_conv : partial[ks] = sum_r (inv_r*mask_r) @ Z_r + root k-slice, M-tile=64,
//           levq staged in LDS, A fragments via v_perm_b32; plain f32 stores
//           (NSLAB=8) or atomic fallback into one slab (NSLAB=1) if ws is small.
//  k_red  : out = sum_ks partial[ks] + bias (+relu -> bf16 for conv1).

#define NE 10000
#define NM 2048
#define NEPAD 10112   // 79 * 128
#define MTILES64 158  // NEPAD / 64
#define KSPLIT 8

typedef short bf8_t __attribute__((ext_vector_type(8)));
typedef float f16f  __attribute__((ext_vector_type(16)));

__device__ __forceinline__ uint16_t f2bf(float f){
  uint32_t u = __float_as_uint(f);
  u += 0x7FFFu + ((u >> 16) & 1u);
  return (uint16_t)(u >> 16);
}

__device__ __forceinline__ f16f mfma32(bf8_t a, bf8_t b, f16f c){
  return __builtin_amdgcn_mfma_f32_32x32x16_bf16(a, b, c, 0, 0, 0);
}

// ---- transpose + bf16 convert the small weight matrices ----
__global__ __launch_bounds__(256) void k_prep(
    const float* __restrict__ root1, const float* __restrict__ root2,
    const float* __restrict__ W1, const float* __restrict__ W2,
    uint16_t* __restrict__ r1t, uint16_t* __restrict__ r2t,
    uint16_t* __restrict__ w1t, uint16_t* __restrict__ w2t){
  int idx = blockIdx.x*256 + threadIdx.x;
  int slab = idx >> 14;
  int pos  = idx & 16383;
  int d = pos >> 7, k = pos & 127;
  float v; uint16_t* dst;
  if (slab == 0)      { v = root1[k*128 + d]; dst = r1t; }
  else if (slab == 1) { v = root2[k*128 + d]; dst = r2t; }
  else if (slab < 7)  { v = W1[(slab-1)*16384 + k*128 + d]; dst = w1t + (slab-2)*16384; }
  else                { v = W2[(slab-6)*16384 + k*128 + d]; dst = w2t + (slab-7)*16384; }
  dst[pos] = f2bf(v);
}

// ---- 32 rows/block: levq (4-bit, k-major, coalesced), inv, xe->bf16 ----
__global__ __launch_bounds__(256) void k_lev(
    const float* __restrict__ w, const float* __restrict__ xe,
    uint32_t* __restrict__ levq, float* __restrict__ inv,
    uint16_t* __restrict__ xebf){
  int t = threadIdx.x;
  int brow = blockIdx.x * 32;
  int rloc = t >> 3, p = t & 7;          // 8 threads per row
  int row = brow + rloc;
  bool active = row < NE;
  const float* wr = w + (size_t)row * NM;
  unsigned long long cnt = 0ull;         // 5 x 12-bit packed relation counters
  __shared__ uint32_t tile[32][33];

  for (int cp = 0; cp < 8; cp++){        // 8 column-panels of 256 cols
    uint32_t packs[4];
    #pragma unroll
    for (int q = 0; q < 4; q++){
      int gck = cp*32 + p + 8*q;         // global 8-col chunk
      uint32_t L = 0;
      if (active){
        const float4* f = (const float4*)(wr + gck*8);
        float4 f0 = f[0], f1 = f[1];
        float wv[8] = {f0.x,f0.y,f0.z,f0.w, f1.x,f1.y,f1.z,f1.w};
        #pragma unroll
        for (int e = 0; e < 8; e++){
          int s = (int)ceilf(wv[e]*6.0f);          // lev+1 in 1..6
          if (s >= 2) cnt += 1ull << (12*(s-2));   // relations 1..5
          L |= (uint32_t)s << (4*e);               // nibble e = entry e
        }
      }
      packs[q] = L;
    }
    __syncthreads();
    #pragma unroll
    for (int q = 0; q < 4; q++) tile[p + 8*q][rloc] = packs[q];
    __syncthreads();
    // coalesced writeout: thread t -> chunk t>>3, 4 consecutive rows (uint4)
    int ckk = t >> 3;
    int r4  = (t & 7) * 4;
    size_t base = (size_t)(cp*32 + ckk) * NEPAD + brow + r4;
    *(uint4*)(levq + base) = make_uint4(tile[ckk][r4], tile[ckk][r4+1],
                                        tile[ckk][r4+2], tile[ckk][r4+3]);
  }

  // reduce packed counters across the 8 threads of each row
  unsigned long long c = cnt;
  c += __shfl_xor(c, 1);
  c += __shfl_xor(c, 2);
  c += __shfl_xor(c, 4);
  if (p == 0 && row < NEPAD){
    if (active){
      inv[row*8 + 0] = 0.f; inv[row*8 + 6] = 0.f; inv[row*8 + 7] = 0.f;
      #pragma unroll
      for (int r = 1; r <= 5; r++){
        uint32_t cc = (uint32_t)((c >> (12*(r-1))) & 0xFFFull);
        inv[row*8 + r] = cc ? 1.0f/(float)cc : 0.f;
      }
    } else {
      #pragma unroll
      for (int i = 0; i < 8; i++) inv[row*8 + i] = 0.f;
    }
  }

  // xe -> bf16 (+ zero pads)
  int f0i = p * 16;
  if (active){
    union { uint16_t u[16]; uint4 q[2]; } ub;
    #pragma unroll
    for (int j = 0; j < 4; j++){
      float4 a = *(const float4*)(xe + (size_t)row*128 + f0i + j*4);
      ub.u[j*4+0]=f2bf(a.x); ub.u[j*4+1]=f2bf(a.y); ub.u[j*4+2]=f2bf(a.z); ub.u[j*4+3]=f2bf(a.w);
    }
    *(uint4*)(xebf + (size_t)row*128 + f0i)     = ub.q[0];
    *(uint4*)(xebf + (size_t)row*128 + f0i + 8) = ub.q[1];
  } else if (row < NEPAD){
    uint4 z = make_uint4(0,0,0,0);
    *(uint4*)(xebf + (size_t)row*128 + f0i)     = z;
    *(uint4*)(xebf + (size_t)row*128 + f0i + 8) = z;
  }
}

// ---- small GEMM [2048x128]@[128x128]; epilogue: m1 (bias+relu) or zpk pack ----
// zpk pack k-order within chunk: local k j -> pos = (j&1)*4 + (j>>1)
template<bool ABF16>
__global__ __launch_bounds__(256) void k_gemm(
    const float* __restrict__ Af, const uint16_t* __restrict__ Ab,
    const uint16_t* __restrict__ Bm, const uint16_t* __restrict__ Bz,
    const float* __restrict__ bias, uint16_t* __restrict__ m1out,
    uint16_t* __restrict__ zpk){
  int tid = threadIdx.x;
  int lane = tid & 63, wid = tid >> 6;
  int l31 = lane & 31, g = lane >> 5;
  int by = blockIdx.y;
  bool m1path = (Bm != nullptr) && (by == 0);
  int r = (Bm != nullptr) ? by - 1 : by;
  const uint16_t* B = m1path ? Bm : (Bz + (size_t)r*16384);
  int arow = blockIdx.x*128 + wid*32 + l31;

  f16f acc[4];
  #pragma unroll
  for (int n = 0; n < 4; n++)
    #pragma unroll
    for (int i = 0; i < 16; i++) acc[n][i] = 0.f;

  #pragma unroll
  for (int ksI = 0; ksI < 8; ksI++){
    int k0 = ksI*16 + g*8;
    bf8_t a;
    if (ABF16){
      a = *(const bf8_t*)(Ab + (size_t)arow*128 + k0);
    } else {
      const float* ap = Af + (size_t)arow*128 + k0;
      float4 f0 = *(const float4*)ap;
      float4 f1 = *(const float4*)(ap + 4);
      union { uint16_t u[8]; bf8_t v; } ua;
      ua.u[0]=f2bf(f0.x); ua.u[1]=f2bf(f0.y); ua.u[2]=f2bf(f0.z); ua.u[3]=f2bf(f0.w);
      ua.u[4]=f2bf(f1.x); ua.u[5]=f2bf(f1.y); ua.u[6]=f2bf(f1.z); ua.u[7]=f2bf(f1.w);
      a = ua.v;
    }
    #pragma unroll
    for (int n = 0; n < 4; n++){
      bf8_t b = *(const bf8_t*)(B + (size_t)(n*32 + l31)*128 + k0);
      acc[n] = mfma32(a, b, acc[n]);
    }
  }
  #pragma unroll
  for (int n = 0; n < 4; n++){
    int colg = n*32 + l31;
    float bv = m1path ? bias[colg] : 0.f;
    #pragma unroll
    for (int v = 0; v < 16; v++){
      int rowl = (v&3) + 8*(v>>2) + 4*g;
      int rg = blockIdx.x*128 + wid*32 + rowl;   // mole index j
      float val = acc[n][v];
      if (m1path){
        m1out[(size_t)rg*128 + colg] = f2bf(fmaxf(val + bv, 0.f));
      } else {
        int pos = ((rg & 1) << 2) | ((rg & 7) >> 1);
        zpk[(size_t)(r*256 + (rg>>3))*1024 + colg*8 + pos] = f2bf(val);
      }
    }
  }
}

// ---- masked RGCN conv, M-tile=64, levq in LDS, partial-slab stores ----
template<int NSLAB>
__global__ __launch_bounds__(256, 2) void k_conv(
    const uint32_t* __restrict__ levq, const float* __restrict__ inv,
    const uint16_t* __restrict__ zpk, const uint16_t* __restrict__ aroot,
    const uint16_t* __restrict__ rt, float* __restrict__ part){
  int tid = threadIdx.x;
  int lane = tid & 63, wid = tid >> 6;
  int wm = wid >> 1, wn = wid & 1;
  int l31 = lane & 31, g = lane >> 5;
  int brow = blockIdx.x*64;
  int ks = blockIdx.y;          // 0..7
  int kc0 = ks*32;              // first 8-col chunk of this k-slice

  // stage levq slice [32 chunks][64 rows] into LDS (8 KB)
  __shared__ uint32_t lev4[32*64];
  uint32_t stage[8];
  #pragma unroll
  for (int i = 0; i < 8; i++){
    int idx = tid + i*256;
    stage[i] = levq[(size_t)(kc0 + (idx >> 6))*NEPAD + brow + (idx & 63)];
  }
  #pragma unroll
  for (int i = 0; i < 8; i++) lev4[tid + i*256] = stage[i];

  // per-relation byte tables: byte (r+1) of the 8-byte pool = inv_r's lo/hi byte
  int rga = brow + 32*wm + l31;
  uint32_t tlo[5], thi[5];
  #pragma unroll
  for (int r = 1; r <= 5; r++){
    uint32_t bits = (uint32_t)f2bf(inv[(size_t)rga*8 + r]);
    int sh = 8*((r+1)&3);
    tlo[r-1] = (bits & 0xFFu) << sh;
    thi[r-1] = (bits >> 8)    << sh;
  }

  __syncthreads();

  f16f acc[2];
  #pragma unroll
  for (int n = 0; n < 2; n++)
    #pragma unroll
    for (int i = 0; i < 16; i++) acc[n][i] = 0.f;

  const uint16_t* zr0 = zpk + (size_t)(64*wn      + l31)*8;
  const uint16_t* zr1 = zpk + (size_t)(64*wn + 32 + l31)*8;

  #pragma unroll 2
  for (int kk = 0; kk < 16; kk++){
    int kt = kk*2 + g;
    uint32_t L = lev4[kt*64 + 32*wm + l31];
    uint32_t sx = L & 0x0F0F0F0Fu, sy = (L >> 4) & 0x0F0F0F0Fu;
    #pragma unroll
    for (int r = 1; r <= 5; r++){
      size_t zb = (size_t)((r-1)*256 + kc0 + kt) * 1024;
      bf8_t bn0 = *(const bf8_t*)(zr0 + zb);
      bf8_t bn1 = *(const bf8_t*)(zr1 + zb);
      uint32_t TL = tlo[r-1], TH = thi[r-1];
      uint32_t pl, ph, ql, qh;
      if (r < 3){   // table byte at index 2..3 -> low pool (src1)
        pl = __builtin_amdgcn_perm(0u, TL, sx);
        ph = __builtin_amdgcn_perm(0u, TH, sx);
        ql = __builtin_amdgcn_perm(0u, TL, sy);
        qh = __builtin_amdgcn_perm(0u, TH, sy);
      } else {      // table byte at index 4..6 -> high pool (src0)
        pl = __builtin_amdgcn_perm(TL, 0u, sx);
        ph = __builtin_amdgcn_perm(TH, 0u, sx);
        ql = __builtin_amdgcn_perm(TL, 0u, sy);
        qh = __builtin_amdgcn_perm(TH, 0u, sy);
      }
      union { uint32_t u[4]; bf8_t v; } A;
      A.u[0] = __builtin_amdgcn_perm(ph, pl, 0x05010400u);
      A.u[1] = __builtin_amdgcn_perm(ph, pl, 0x07030602u);
      A.u[2] = __builtin_amdgcn_perm(qh, ql, 0x05010400u);
      A.u[3] = __builtin_amdgcn_perm(qh, ql, 0x07030602u);
      acc[0] = mfma32(A.v, bn0, acc[0]);
      acc[1] = mfma32(A.v, bn1, acc[1]);
    }
  }

  {  // this block's root-matmul k-slice (16 of 128)
    int k0 = ks*16 + g*8;
    bf8_t a0  = *(const bf8_t*)(aroot + (size_t)rga*128 + k0);
    bf8_t rb0 = *(const bf8_t*)(rt + (size_t)(64*wn      + l31)*128 + k0);
    bf8_t rb1 = *(const bf8_t*)(rt + (size_t)(64*wn + 32 + l31)*128 + k0);
    acc[0] = mfma32(a0, rb0, acc[0]);
    acc[1] = mfma32(a0, rb1, acc[1]);
  }

  float* dst = part + ((NSLAB == 8) ? (size_t)ks*NEPAD*128 : 0);
  #pragma unroll
  for (int nt = 0; nt < 2; nt++){
    int colg = 64*wn + 32*nt + l31;
    #pragma unroll
    for (int v = 0; v < 16; v++){
      int rowl = (v&3) + 8*(v>>2) + 4*g;
      size_t o = (size_t)(brow + 32*wm + rowl)*128 + colg;
      if (NSLAB == 8) dst[o] = acc[nt][v];
      else            unsafeAtomicAdd(&dst[o], acc[nt][v]);
    }
  }
}

// ---- reduce partial slabs + bias; C1: relu->bf16 (e1), else f32 -> d_out ----
template<bool C1, int KS>
__global__ __launch_bounds__(256) void k_red(
    const float* __restrict__ part, const float* __restrict__ bias,
    uint16_t* __restrict__ e1bf, float* __restrict__ out){
  size_t idx4 = ((size_t)blockIdx.x*256 + threadIdx.x) * 4;   // < NEPAD*128
  int col = (int)(idx4 & 127);
  float4 s = *(const float4*)(part + idx4);
  #pragma unroll
  for (int k = 1; k < KS; k++){
    float4 p = *(const float4*)(part + (size_t)k*NEPAD*128 + idx4);
    s.x += p.x; s.y += p.y; s.z += p.z; s.w += p.w;
  }
  float4 b = *(const float4*)(bias + col);
  s.x += b.x; s.y += b.y; s.z += b.z; s.w += b.w;
  if (C1){
    union { uint16_t u[4]; uint2 q; } ub;
    ub.u[0] = f2bf(fmaxf(s.x, 0.f));
    ub.u[1] = f2bf(fmaxf(s.y, 0.f));
    ub.u[2] = f2bf(fmaxf(s.z, 0.f));
    ub.u[3] = f2bf(fmaxf(s.w, 0.f));
    *(uint2*)(e1bf + idx4) = ub.q;
  } else {
    if (idx4 < (size_t)NE*128) *(float4*)(out + idx4) = s;
  }
}

extern "C" void kernel_launch(void* const* d_in, const int* in_sizes, int n_in,
                              void* d_out, int out_size, void* d_ws, size_t ws_size,
                              hipStream_t stream){
  const float* xe  = (const float*)d_in[0];
  const float* xm  = (const float*)d_in[1];
  const float* w   = (const float*)d_in[2];
  const float* W1  = (const float*)d_in[3];
  const float* r1  = (const float*)d_in[4];
  const float* b1  = (const float*)d_in[5];
  const float* W2  = (const float*)d_in[6];
  const float* r2  = (const float*)d_in[7];
  const float* b2  = (const float*)d_in[8];
  float* out = (float*)d_out;
  char* ws = (char*)d_ws;

  constexpr size_t OFF_INV  = 0;                                   // NEPAD*8*4
  constexpr size_t OFF_XEBF = OFF_INV  + (size_t)NEPAD*8*4;        // NEPAD*128*2 (also e1bf)
  constexpr size_t OFF_M1   = OFF_XEBF + (size_t)NEPAD*128*2;      // NM*128*2
  constexpr size_t OFF_Z1   = OFF_M1   + (size_t)NM*128*2;         // 5*NM*128*2
  constexpr size_t OFF_Z2   = OFF_Z1   + (size_t)5*NM*128*2;       // 5*NM*128*2
  constexpr size_t OFF_R1T  = OFF_Z2   + (size_t)5*NM*128*2;
  constexpr size_t OFF_R2T  = OFF_R1T  + 128*128*2;
  constexpr size_t OFF_W1T  = OFF_R2T  + 128*128*2;
  constexpr size_t OFF_W2T  = OFF_W1T  + (size_t)5*128*128*2;
  constexpr size_t OFF_LEVQ = OFF_W2T  + (size_t)5*128*128*2;      // 256*NEPAD*4 (~10.4MB)
  constexpr size_t OFF_PART = OFF_LEVQ + (size_t)256*NEPAD*4;
  constexpr size_t SLAB     = (size_t)NEPAD*128*4;                 // 5.18 MB
  constexpr size_t NEED_A   = OFF_PART + 8*SLAB;                   // ~60.8 MB
  // fallback (NSLAB=1, atomic): OFF_PART + SLAB ~ 24.6 MB

  float*    inv  = (float*)   (ws + OFF_INV);
  uint16_t* xebf = (uint16_t*)(ws + OFF_XEBF);
  uint16_t* m1   = (uint16_t*)(ws + OFF_M1);
  uint16_t* z1   = (uint16_t*)(ws + OFF_Z1);
  uint16_t* z2   = (uint16_t*)(ws + OFF_Z2);
  uint16_t* r1t  = (uint16_t*)(ws + OFF_R1T);
  uint16_t* r2t  = (uint16_t*)(ws + OFF_R2T);
  uint16_t* w1t  = (uint16_t*)(ws + OFF_W1T);
  uint16_t* w2t  = (uint16_t*)(ws + OFF_W2T);
  uint32_t* levq = (uint32_t*)(ws + OFF_LEVQ);
  float*    part = (float*)   (ws + OFF_PART);

  bool tierA = (ws_size >= NEED_A);

  hipLaunchKernelGGL(k_prep, dim3(768), dim3(256), 0, stream,
                     r1, r2, W1, W2, r1t, r2t, w1t, w2t);
  hipLaunchKernelGGL(k_lev, dim3(NEPAD/32), dim3(256), 0, stream,
                     w, xe, levq, inv, xebf);
  // y=0: m1 = relu(xm@root1+b1); y=1..5: z1[y-1] = pack(xm@W1[y-1])
  hipLaunchKernelGGL((k_gemm<false>), dim3(16,6), dim3(256), 0, stream,
                     xm, (const uint16_t*)nullptr, r1t, w1t, b1, m1, z1);
  // z2[r] = pack(m1@W2[r])
  hipLaunchKernelGGL((k_gemm<true>), dim3(16,5), dim3(256), 0, stream,
                     (const float*)nullptr, m1, (const uint16_t*)nullptr, w2t,
                     (const float*)nullptr, (uint16_t*)nullptr, z2);
  if (tierA){
    // conv1 partials, reduce(+b1, relu) -> e1bf (xebf reused)
    hipLaunchKernelGGL((k_conv<8>), dim3(MTILES64, KSPLIT), dim3(256), 0, stream,
                       levq, inv, z1, xebf, r1t, part);
    hipLaunchKernelGGL((k_red<true,8>), dim3(NEPAD*128/1024), dim3(256), 0, stream,
                       part, b1, xebf, (float*)nullptr);
    // conv2 partials, reduce(+b2) -> out
    hipLaunchKernelGGL((k_conv<8>), dim3(MTILES64, KSPLIT), dim3(256), 0, stream,
                       levq, inv, z2, xebf, r2t, part);
    hipLaunchKernelGGL((k_red<false,8>), dim3(NEPAD*128/1024), dim3(256), 0, stream,
                       part, b2, (uint16_t*)nullptr, out);
  } else {
    hipMemsetAsync(part, 0, SLAB, stream);
    hipLaunchKernelGGL((k_conv<1>), dim3(MTILES64, KSPLIT), dim3(256), 0, stream,
                       levq, inv, z1, xebf, r1t, part);
    hipLaunchKernelGGL((k_red<true,1>), dim3(NEPAD*128/1024), dim3(256), 0, stream,
                       part, b1, xebf, (float*)nullptr);
    hipMemsetAsync(part, 0, SLAB, stream);
    hipLaunchKernelGGL((k_conv<1>), dim3(MTILES64, KSPLIT), dim3(256), 0, stream,
                       levq, inv, z2, xebf, r2t, part);
    hipLaunchKernelGGL((k_red<false,1>), dim3(NEPAD*128/1024), dim3(256), 0, stream,
                       part, b2, (uint16_t*)nullptr, out);
  }
}

// Round 5
// 154.691 us; speedup vs baseline: 1.4865x; 1.1680x over previous
//
#include <hip/hip_runtime.h>
#include <stdint.h>

// hetero_effect_graph: 2-layer RGCN over dense level-partitioned bipartite graph.
//  k_prep : transpose+bf16 root1,root2,W1[1..5],W2[1..5]
//  k_lev  : sel = ceil(w*6) in 0..6, 4-bit packed k-major (levq[k/8][row] u32,
//           coalesced via LDS tile transpose), relation counts -> inv, xe->bf16
//  k_gemm : m1 = relu(xm@root1+b1); z[r] = (A@W[r]) packed k-major [r][k/8][d][8]
//           with k-order [0,2,4,6,1,3,5,7] inside each 8-chunk (matches nibble unpack)
//  k_conv : 1-wave blocks, wave = 32M x 128N: per (kk,r) 8 perms feed 4 MFMA
//           (A-build amortized over full N; z-load dup eliminated; lev straight
//           from global). partial[ks] slabs, plain stores (atomic fallback).
//  k_red  : out = sum_ks partial[ks] + bias (+relu -> bf16 for conv1).

#define NE 10000
#define NM 2048
#define NEPAD 10112   // 79 * 128
#define MTILES32 316  // NEPAD / 32
#define KSPLIT 8

typedef short bf8_t __attribute__((ext_vector_type(8)));
typedef float f16f  __attribute__((ext_vector_type(16)));

__device__ __forceinline__ uint16_t f2bf(float f){
  uint32_t u = __float_as_uint(f);
  u += 0x7FFFu + ((u >> 16) & 1u);
  return (uint16_t)(u >> 16);
}

__device__ __forceinline__ f16f mfma32(bf8_t a, bf8_t b, f16f c){
  return __builtin_amdgcn_mfma_f32_32x32x16_bf16(a, b, c, 0, 0, 0);
}

// ---- transpose + bf16 convert the small weight matrices ----
__global__ __launch_bounds__(256) void k_prep(
    const float* __restrict__ root1, const float* __restrict__ root2,
    const float* __restrict__ W1, const float* __restrict__ W2,
    uint16_t* __restrict__ r1t, uint16_t* __restrict__ r2t,
    uint16_t* __restrict__ w1t, uint16_t* __restrict__ w2t){
  int idx = blockIdx.x*256 + threadIdx.x;
  int slab = idx >> 14;
  int pos  = idx & 16383;
  int d = pos >> 7, k = pos & 127;
  float v; uint16_t* dst;
  if (slab == 0)      { v = root1[k*128 + d]; dst = r1t; }
  else if (slab == 1) { v = root2[k*128 + d]; dst = r2t; }
  else if (slab < 7)  { v = W1[(slab-1)*16384 + k*128 + d]; dst = w1t + (slab-2)*16384; }
  else                { v = W2[(slab-6)*16384 + k*128 + d]; dst = w2t + (slab-7)*16384; }
  dst[pos] = f2bf(v);
}

// ---- 32 rows/block: levq (4-bit, k-major, coalesced), inv, xe->bf16 ----
__global__ __launch_bounds__(256) void k_lev(
    const float* __restrict__ w, const float* __restrict__ xe,
    uint32_t* __restrict__ levq, float* __restrict__ inv,
    uint16_t* __restrict__ xebf){
  int t = threadIdx.x;
  int brow = blockIdx.x * 32;
  int rloc = t >> 3, p = t & 7;          // 8 threads per row
  int row = brow + rloc;
  bool active = row < NE;
  const float* wr = w + (size_t)row * NM;
  unsigned long long cnt = 0ull;         // 5 x 12-bit packed relation counters
  __shared__ uint32_t tile[32][33];

  for (int cp = 0; cp < 8; cp++){        // 8 column-panels of 256 cols
    uint32_t packs[4];
    #pragma unroll
    for (int q = 0; q < 4; q++){
      int gck = cp*32 + p + 8*q;         // global 8-col chunk
      uint32_t L = 0;
      if (active){
        const float4* f = (const float4*)(wr + gck*8);
        float4 f0 = f[0], f1 = f[1];
        float wv[8] = {f0.x,f0.y,f0.z,f0.w, f1.x,f1.y,f1.z,f1.w};
        #pragma unroll
        for (int e = 0; e < 8; e++){
          int s = (int)ceilf(wv[e]*6.0f);          // lev+1 in 1..6
          if (s >= 2) cnt += 1ull << (12*(s-2));   // relations 1..5
          L |= (uint32_t)s << (4*e);               // nibble e = entry e
        }
      }
      packs[q] = L;
    }
    __syncthreads();
    #pragma unroll
    for (int q = 0; q < 4; q++) tile[p + 8*q][rloc] = packs[q];
    __syncthreads();
    // coalesced writeout: thread t -> chunk t>>3, 4 consecutive rows (uint4)
    int ckk = t >> 3;
    int r4  = (t & 7) * 4;
    size_t base = (size_t)(cp*32 + ckk) * NEPAD + brow + r4;
    *(uint4*)(levq + base) = make_uint4(tile[ckk][r4], tile[ckk][r4+1],
                                        tile[ckk][r4+2], tile[ckk][r4+3]);
  }

  // reduce packed counters across the 8 threads of each row
  unsigned long long c = cnt;
  c += __shfl_xor(c, 1);
  c += __shfl_xor(c, 2);
  c += __shfl_xor(c, 4);
  if (p == 0 && row < NEPAD){
    if (active){
      inv[row*8 + 0] = 0.f; inv[row*8 + 6] = 0.f; inv[row*8 + 7] = 0.f;
      #pragma unroll
      for (int r = 1; r <= 5; r++){
        uint32_t cc = (uint32_t)((c >> (12*(r-1))) & 0xFFFull);
        inv[row*8 + r] = cc ? 1.0f/(float)cc : 0.f;
      }
    } else {
      #pragma unroll
      for (int i = 0; i < 8; i++) inv[row*8 + i] = 0.f;
    }
  }

  // xe -> bf16 (+ zero pads)
  int f0i = p * 16;
  if (active){
    union { uint16_t u[16]; uint4 q[2]; } ub;
    #pragma unroll
    for (int j = 0; j < 4; j++){
      float4 a = *(const float4*)(xe + (size_t)row*128 + f0i + j*4);
      ub.u[j*4+0]=f2bf(a.x); ub.u[j*4+1]=f2bf(a.y); ub.u[j*4+2]=f2bf(a.z); ub.u[j*4+3]=f2bf(a.w);
    }
    *(uint4*)(xebf + (size_t)row*128 + f0i)     = ub.q[0];
    *(uint4*)(xebf + (size_t)row*128 + f0i + 8) = ub.q[1];
  } else if (row < NEPAD){
    uint4 z = make_uint4(0,0,0,0);
    *(uint4*)(xebf + (size_t)row*128 + f0i)     = z;
    *(uint4*)(xebf + (size_t)row*128 + f0i + 8) = z;
  }
}

// ---- small GEMM [2048x128]@[128x128]; epilogue: m1 (bias+relu) or zpk pack ----
// zpk pack k-order within chunk: local k j -> pos = (j&1)*4 + (j>>1)
template<bool ABF16>
__global__ __launch_bounds__(256) void k_gemm(
    const float* __restrict__ Af, const uint16_t* __restrict__ Ab,
    const uint16_t* __restrict__ Bm, const uint16_t* __restrict__ Bz,
    const float* __restrict__ bias, uint16_t* __restrict__ m1out,
    uint16_t* __restrict__ zpk){
  int tid = threadIdx.x;
  int lane = tid & 63, wid = tid >> 6;
  int l31 = lane & 31, g = lane >> 5;
  int by = blockIdx.y;
  bool m1path = (Bm != nullptr) && (by == 0);
  int r = (Bm != nullptr) ? by - 1 : by;
  const uint16_t* B = m1path ? Bm : (Bz + (size_t)r*16384);
  int arow = blockIdx.x*128 + wid*32 + l31;

  f16f acc[4];
  #pragma unroll
  for (int n = 0; n < 4; n++)
    #pragma unroll
    for (int i = 0; i < 16; i++) acc[n][i] = 0.f;

  #pragma unroll
  for (int ksI = 0; ksI < 8; ksI++){
    int k0 = ksI*16 + g*8;
    bf8_t a;
    if (ABF16){
      a = *(const bf8_t*)(Ab + (size_t)arow*128 + k0);
    } else {
      const float* ap = Af + (size_t)arow*128 + k0;
      float4 f0 = *(const float4*)ap;
      float4 f1 = *(const float4*)(ap + 4);
      union { uint16_t u[8]; bf8_t v; } ua;
      ua.u[0]=f2bf(f0.x); ua.u[1]=f2bf(f0.y); ua.u[2]=f2bf(f0.z); ua.u[3]=f2bf(f0.w);
      ua.u[4]=f2bf(f1.x); ua.u[5]=f2bf(f1.y); ua.u[6]=f2bf(f1.z); ua.u[7]=f2bf(f1.w);
      a = ua.v;
    }
    #pragma unroll
    for (int n = 0; n < 4; n++){
      bf8_t b = *(const bf8_t*)(B + (size_t)(n*32 + l31)*128 + k0);
      acc[n] = mfma32(a, b, acc[n]);
    }
  }
  #pragma unroll
  for (int n = 0; n < 4; n++){
    int colg = n*32 + l31;
    float bv = m1path ? bias[colg] : 0.f;
    #pragma unroll
    for (int v = 0; v < 16; v++){
      int rowl = (v&3) + 8*(v>>2) + 4*g;
      int rg = blockIdx.x*128 + wid*32 + rowl;   // mole index j
      float val = acc[n][v];
      if (m1path){
        m1out[(size_t)rg*128 + colg] = f2bf(fmaxf(val + bv, 0.f));
      } else {
        int pos = ((rg & 1) << 2) | ((rg & 7) >> 1);
        zpk[(size_t)(r*256 + (rg>>3))*1024 + colg*8 + pos] = f2bf(val);
      }
    }
  }
}

// ---- masked RGCN conv: 1 wave = 32M x 128N, perms amortized over 4 MFMA ----
template<int NSLAB>
__global__ __launch_bounds__(64, 4) void k_conv(
    const uint32_t* __restrict__ levq, const float* __restrict__ inv,
    const uint16_t* __restrict__ zpk, const uint16_t* __restrict__ aroot,
    const uint16_t* __restrict__ rt, float* __restrict__ part){
  int lane = threadIdx.x;
  int l31 = lane & 31, g = lane >> 5;
  int brow = blockIdx.x*32;
  int ks = blockIdx.y;          // 0..7
  int kc0 = ks*32;              // first 8-col chunk of this k-slice
  int row = brow + l31;

  // per-relation byte tables: byte (r+1) of the 8-byte pool = inv_r's lo/hi byte
  uint32_t tlo[5], thi[5];
  #pragma unroll
  for (int r = 1; r <= 5; r++){
    uint32_t bits = (uint32_t)f2bf(inv[(size_t)row*8 + r]);
    int sh = 8*((r+1)&3);
    tlo[r-1] = (bits & 0xFFu) << sh;
    thi[r-1] = (bits >> 8)    << sh;
  }

  f16f acc[4];
  #pragma unroll
  for (int n = 0; n < 4; n++)
    #pragma unroll
    for (int i = 0; i < 16; i++) acc[n][i] = 0.f;

  const uint16_t* zc = zpk + (size_t)l31*8;   // column base within a chunk

  #pragma unroll 2
  for (int kk = 0; kk < 16; kk++){
    int kt = kc0 + kk*2 + g;
    uint32_t L = levq[(size_t)kt*NEPAD + row];
    uint32_t sx = L & 0x0F0F0F0Fu, sy = (L >> 4) & 0x0F0F0F0Fu;
    #pragma unroll
    for (int r = 1; r <= 5; r++){
      size_t zb = (size_t)((r-1)*256 + kt) * 1024;
      bf8_t b0 = *(const bf8_t*)(zc + zb);
      bf8_t b1 = *(const bf8_t*)(zc + zb + 256);
      bf8_t b2 = *(const bf8_t*)(zc + zb + 512);
      bf8_t b3 = *(const bf8_t*)(zc + zb + 768);
      uint32_t TL = tlo[r-1], TH = thi[r-1];
      uint32_t pl, ph, ql, qh;
      if (r < 3){   // table byte at index 2..3 -> low pool (src1)
        pl = __builtin_amdgcn_perm(0u, TL, sx);
        ph = __builtin_amdgcn_perm(0u, TH, sx);
        ql = __builtin_amdgcn_perm(0u, TL, sy);
        qh = __builtin_amdgcn_perm(0u, TH, sy);
      } else {      // table byte at index 4..6 -> high pool (src0)
        pl = __builtin_amdgcn_perm(TL, 0u, sx);
        ph = __builtin_amdgcn_perm(TH, 0u, sx);
        ql = __builtin_amdgcn_perm(TL, 0u, sy);
        qh = __builtin_amdgcn_perm(TH, 0u, sy);
      }
      union { uint32_t u[4]; bf8_t v; } A;
      A.u[0] = __builtin_amdgcn_perm(ph, pl, 0x05010400u);
      A.u[1] = __builtin_amdgcn_perm(ph, pl, 0x07030602u);
      A.u[2] = __builtin_amdgcn_perm(qh, ql, 0x05010400u);
      A.u[3] = __builtin_amdgcn_perm(qh, ql, 0x07030602u);
      acc[0] = mfma32(A.v, b0, acc[0]);
      acc[1] = mfma32(A.v, b1, acc[1]);
      acc[2] = mfma32(A.v, b2, acc[2]);
      acc[3] = mfma32(A.v, b3, acc[3]);
    }
  }

  {  // this block's root-matmul k-slice (16 of 128)
    int k0 = ks*16 + g*8;
    bf8_t a = *(const bf8_t*)(aroot + (size_t)row*128 + k0);
    #pragma unroll
    for (int nt = 0; nt < 4; nt++){
      bf8_t rb = *(const bf8_t*)(rt + (size_t)(nt*32 + l31)*128 + k0);
      acc[nt] = mfma32(a, rb, acc[nt]);
    }
  }

  float* dst = part + ((NSLAB == 8) ? (size_t)ks*NEPAD*128 : 0);
  #pragma unroll
  for (int nt = 0; nt < 4; nt++){
    int colg = nt*32 + l31;
    #pragma unroll
    for (int v = 0; v < 16; v++){
      int rowl = (v&3) + 8*(v>>2) + 4*g;
      size_t o = (size_t)(brow + rowl)*128 + colg;
      if (NSLAB == 8) dst[o] = acc[nt][v];
      else            unsafeAtomicAdd(&dst[o], acc[nt][v]);
    }
  }
}

// ---- reduce partial slabs + bias; C1: relu->bf16 (e1), else f32 -> d_out ----
template<bool C1, int KS>
__global__ __launch_bounds__(256) void k_red(
    const float* __restrict__ part, const float* __restrict__ bias,
    uint16_t* __restrict__ e1bf, float* __restrict__ out){
  size_t idx4 = ((size_t)blockIdx.x*256 + threadIdx.x) * 4;   // < NEPAD*128
  int col = (int)(idx4 & 127);
  float4 s = *(const float4*)(part + idx4);
  #pragma unroll
  for (int k = 1; k < KS; k++){
    float4 p = *(const float4*)(part + (size_t)k*NEPAD*128 + idx4);
    s.x += p.x; s.y += p.y; s.z += p.z; s.w += p.w;
  }
  float4 b = *(const float4*)(bias + col);
  s.x += b.x; s.y += b.y; s.z += b.z; s.w += b.w;
  if (C1){
    union { uint16_t u[4]; uint2 q; } ub;
    ub.u[0] = f2bf(fmaxf(s.x, 0.f));
    ub.u[1] = f2bf(fmaxf(s.y, 0.f));
    ub.u[2] = f2bf(fmaxf(s.z, 0.f));
    ub.u[3] = f2bf(fmaxf(s.w, 0.f));
    *(uint2*)(e1bf + idx4) = ub.q;
  } else {
    if (idx4 < (size_t)NE*128) *(float4*)(out + idx4) = s;
  }
}

extern "C" void kernel_launch(void* const* d_in, const int* in_sizes, int n_in,
                              void* d_out, int out_size, void* d_ws, size_t ws_size,
                              hipStream_t stream){
  const float* xe  = (const float*)d_in[0];
  const float* xm  = (const float*)d_in[1];
  const float* w   = (const float*)d_in[2];
  const float* W1  = (const float*)d_in[3];
  const float* r1  = (const float*)d_in[4];
  const float* b1  = (const float*)d_in[5];
  const float* W2  = (const float*)d_in[6];
  const float* r2  = (const float*)d_in[7];
  const float* b2  = (const float*)d_in[8];
  float* out = (float*)d_out;
  char* ws = (char*)d_ws;

  constexpr size_t OFF_INV  = 0;                                   // NEPAD*8*4
  constexpr size_t OFF_XEBF = OFF_INV  + (size_t)NEPAD*8*4;        // NEPAD*128*2 (also e1bf)
  constexpr size_t OFF_M1   = OFF_XEBF + (size_t)NEPAD*128*2;      // NM*128*2
  constexpr size_t OFF_Z1   = OFF_M1   + (size_t)NM*128*2;         // 5*NM*128*2
  constexpr size_t OFF_Z2   = OFF_Z1   + (size_t)5*NM*128*2;       // 5*NM*128*2
  constexpr size_t OFF_R1T  = OFF_Z2   + (size_t)5*NM*128*2;
  constexpr size_t OFF_R2T  = OFF_R1T  + 128*128*2;
  constexpr size_t OFF_W1T  = OFF_R2T  + 128*128*2;
  constexpr size_t OFF_W2T  = OFF_W1T  + (size_t)5*128*128*2;
  constexpr size_t OFF_LEVQ = OFF_W2T  + (size_t)5*128*128*2;      // 256*NEPAD*4 (~10.4MB)
  constexpr size_t OFF_PART = OFF_LEVQ + (size_t)256*NEPAD*4;
  constexpr size_t SLAB     = (size_t)NEPAD*128*4;                 // 5.18 MB
  constexpr size_t NEED_A   = OFF_PART + 8*SLAB;                   // ~60.8 MB
  // fallback (NSLAB=1, atomic): OFF_PART + SLAB ~ 24.6 MB

  float*    inv  = (float*)   (ws + OFF_INV);
  uint16_t* xebf = (uint16_t*)(ws + OFF_XEBF);
  uint16_t* m1   = (uint16_t*)(ws + OFF_M1);
  uint16_t* z1   = (uint16_t*)(ws + OFF_Z1);
  uint16_t* z2   = (uint16_t*)(ws + OFF_Z2);
  uint16_t* r1t  = (uint16_t*)(ws + OFF_R1T);
  uint16_t* r2t  = (uint16_t*)(ws + OFF_R2T);
  uint16_t* w1t  = (uint16_t*)(ws + OFF_W1T);
  uint16_t* w2t  = (uint16_t*)(ws + OFF_W2T);
  uint32_t* levq = (uint32_t*)(ws + OFF_LEVQ);
  float*    part = (float*)   (ws + OFF_PART);

  bool tierA = (ws_size >= NEED_A);

  hipLaunchKernelGGL(k_prep, dim3(768), dim3(256), 0, stream,
                     r1, r2, W1, W2, r1t, r2t, w1t, w2t);
  hipLaunchKernelGGL(k_lev, dim3(NEPAD/32), dim3(256), 0, stream,
                     w, xe, levq, inv, xebf);
  // y=0: m1 = relu(xm@root1+b1); y=1..5: z1[y-1] = pack(xm@W1[y-1])
  hipLaunchKernelGGL((k_gemm<false>), dim3(16,6), dim3(256), 0, stream,
                     xm, (const uint16_t*)nullptr, r1t, w1t, b1, m1, z1);
  // z2[r] = pack(m1@W2[r])
  hipLaunchKernelGGL((k_gemm<true>), dim3(16,5), dim3(256), 0, stream,
                     (const float*)nullptr, m1, (const uint16_t*)nullptr, w2t,
                     (const float*)nullptr, (uint16_t*)nullptr, z2);
  if (tierA){
    // conv1 partials, reduce(+b1, relu) -> e1bf (xebf reused)
    hipLaunchKernelGGL((k_conv<8>), dim3(MTILES32, KSPLIT), dim3(64), 0, stream,
                       levq, inv, z1, xebf, r1t, part);
    hipLaunchKernelGGL((k_red<true,8>), dim3(NEPAD*128/1024), dim3(256), 0, stream,
                       part, b1, xebf, (float*)nullptr);
    // conv2 partials, reduce(+b2) -> out
    hipLaunchKernelGGL((k_conv<8>), dim3(MTILES32, KSPLIT), dim3(64), 0, stream,
                       levq, inv, z2, xebf, r2t, part);
    hipLaunchKernelGGL((k_red<false,8>), dim3(NEPAD*128/1024), dim3(256), 0, stream,
                       part, b2, (uint16_t*)nullptr, out);
  } else {
    hipMemsetAsync(part, 0, SLAB, stream);
    hipLaunchKernelGGL((k_conv<1>), dim3(MTILES32, KSPLIT), dim3(64), 0, stream,
                       levq, inv, z1, xebf, r1t, part);
    hipLaunchKernelGGL((k_red<true,1>), dim3(NEPAD*128/1024), dim3(256), 0, stream,
                       part, b1, xebf, (float*)nullptr);
    hipMemsetAsync(part, 0, SLAB, stream);
    hipLaunchKernelGGL((k_conv<1>), dim3(MTILES32, KSPLIT), dim3(64), 0, stream,
                       levq, inv, z2, xebf, r2t, part);
    hipLaunchKernelGGL((k_red<false,1>), dim3(NEPAD*128/1024), dim3(256), 0, stream,
                       part, b2, (uint16_t*)nullptr, out);
  }
}

// Round 6
// 138.024 us; speedup vs baseline: 1.6660x; 1.1207x over previous
//
#include <hip/hip_runtime.h>
#include <stdint.h>

// hetero_effect_graph: 2-layer RGCN over dense level-partitioned bipartite graph.
//  k_prep : transpose+bf16 root1,root2,W1[1..5],W2[1..5]
//  k_lev  : sel = ceil(w*6) in 0..6, 4-bit packed k-major (levq[k/8][row] u32),
//           relation counts -> inv, xe->bf16
//  k_gemm : m1 = relu(xm@root1+b1); z[r] = (A@W[r]) packed k-major [r][k/8][d][8]
//  k_conv : 2-wave blocks (128M x 128N), M=64/wave; Z ks-slice double-buffered in
//           LDS (reg-staged, T14 issue-early/write-late); A fragments via perm
//           byte tables; KSPLIT=16; bf16 partial slabs (atomic f32 fallback).
//  k_red  : out = sum_16 slabs + bias (+relu -> bf16 e1 for conv1).

#define NE 10000
#define NM 2048
#define NEPAD 10112   // 79 * 128
#define KSPLIT 16

typedef short bf8_t __attribute__((ext_vector_type(8)));
typedef float f16f  __attribute__((ext_vector_type(16)));

__device__ __forceinline__ uint16_t f2bf(float f){
  uint32_t u = __float_as_uint(f);
  u += 0x7FFFu + ((u >> 16) & 1u);
  return (uint16_t)(u >> 16);
}

__device__ __forceinline__ f16f mfma32(bf8_t a, bf8_t b, f16f c){
  return __builtin_amdgcn_mfma_f32_32x32x16_bf16(a, b, c, 0, 0, 0);
}

// ---- transpose + bf16 convert the small weight matrices ----
__global__ __launch_bounds__(256) void k_prep(
    const float* __restrict__ root1, const float* __restrict__ root2,
    const float* __restrict__ W1, const float* __restrict__ W2,
    uint16_t* __restrict__ r1t, uint16_t* __restrict__ r2t,
    uint16_t* __restrict__ w1t, uint16_t* __restrict__ w2t){
  int idx = blockIdx.x*256 + threadIdx.x;
  int slab = idx >> 14;
  int pos  = idx & 16383;
  int d = pos >> 7, k = pos & 127;
  float v; uint16_t* dst;
  if (slab == 0)      { v = root1[k*128 + d]; dst = r1t; }
  else if (slab == 1) { v = root2[k*128 + d]; dst = r2t; }
  else if (slab < 7)  { v = W1[(slab-1)*16384 + k*128 + d]; dst = w1t + (slab-2)*16384; }
  else                { v = W2[(slab-6)*16384 + k*128 + d]; dst = w2t + (slab-7)*16384; }
  dst[pos] = f2bf(v);
}

// ---- 32 rows/block: levq (4-bit, k-major, coalesced), inv, xe->bf16 ----
__global__ __launch_bounds__(256) void k_lev(
    const float* __restrict__ w, const float* __restrict__ xe,
    uint32_t* __restrict__ levq, float* __restrict__ inv,
    uint16_t* __restrict__ xebf){
  int t = threadIdx.x;
  int brow = blockIdx.x * 32;
  int rloc = t >> 3, p = t & 7;          // 8 threads per row
  int row = brow + rloc;
  bool active = row < NE;
  const float* wr = w + (size_t)row * NM;
  unsigned long long cnt = 0ull;         // 5 x 12-bit packed relation counters
  __shared__ uint32_t tile[32][33];

  for (int cp = 0; cp < 8; cp++){        // 8 column-panels of 256 cols
    uint32_t packs[4];
    #pragma unroll
    for (int q = 0; q < 4; q++){
      int gck = cp*32 + p + 8*q;         // global 8-col chunk
      uint32_t L = 0;
      if (active){
        const float4* f = (const float4*)(wr + gck*8);
        float4 f0 = f[0], f1 = f[1];
        float wv[8] = {f0.x,f0.y,f0.z,f0.w, f1.x,f1.y,f1.z,f1.w};
        #pragma unroll
        for (int e = 0; e < 8; e++){
          int s = (int)ceilf(wv[e]*6.0f);          // lev+1 in 1..6
          if (s >= 2) cnt += 1ull << (12*(s-2));   // relations 1..5
          L |= (uint32_t)s << (4*e);               // nibble e = entry e
        }
      }
      packs[q] = L;
    }
    __syncthreads();
    #pragma unroll
    for (int q = 0; q < 4; q++) tile[p + 8*q][rloc] = packs[q];
    __syncthreads();
    int ckk = t >> 3;
    int r4  = (t & 7) * 4;
    size_t base = (size_t)(cp*32 + ckk) * NEPAD + brow + r4;
    *(uint4*)(levq + base) = make_uint4(tile[ckk][r4], tile[ckk][r4+1],
                                        tile[ckk][r4+2], tile[ckk][r4+3]);
  }

  unsigned long long c = cnt;
  c += __shfl_xor(c, 1);
  c += __shfl_xor(c, 2);
  c += __shfl_xor(c, 4);
  if (p == 0 && row < NEPAD){
    if (active){
      inv[row*8 + 0] = 0.f; inv[row*8 + 6] = 0.f; inv[row*8 + 7] = 0.f;
      #pragma unroll
      for (int r = 1; r <= 5; r++){
        uint32_t cc = (uint32_t)((c >> (12*(r-1))) & 0xFFFull);
        inv[row*8 + r] = cc ? 1.0f/(float)cc : 0.f;
      }
    } else {
      #pragma unroll
      for (int i = 0; i < 8; i++) inv[row*8 + i] = 0.f;
    }
  }

  int f0i = p * 16;
  if (active){
    union { uint16_t u[16]; uint4 q[2]; } ub;
    #pragma unroll
    for (int j = 0; j < 4; j++){
      float4 a = *(const float4*)(xe + (size_t)row*128 + f0i + j*4);
      ub.u[j*4+0]=f2bf(a.x); ub.u[j*4+1]=f2bf(a.y); ub.u[j*4+2]=f2bf(a.z); ub.u[j*4+3]=f2bf(a.w);
    }
    *(uint4*)(xebf + (size_t)row*128 + f0i)     = ub.q[0];
    *(uint4*)(xebf + (size_t)row*128 + f0i + 8) = ub.q[1];
  } else if (row < NEPAD){
    uint4 z = make_uint4(0,0,0,0);
    *(uint4*)(xebf + (size_t)row*128 + f0i)     = z;
    *(uint4*)(xebf + (size_t)row*128 + f0i + 8) = z;
  }
}

// ---- small GEMM [2048x128]@[128x128]; epilogue: m1 (bias+relu) or zpk pack ----
// zpk pack k-order within chunk: local k j -> pos = (j&1)*4 + (j>>1)
template<bool ABF16>
__global__ __launch_bounds__(256) void k_gemm(
    const float* __restrict__ Af, const uint16_t* __restrict__ Ab,
    const uint16_t* __restrict__ Bm, const uint16_t* __restrict__ Bz,
    const float* __restrict__ bias, uint16_t* __restrict__ m1out,
    uint16_t* __restrict__ zpk){
  int tid = threadIdx.x;
  int lane = tid & 63, wid = tid >> 6;
  int l31 = lane & 31, g = lane >> 5;
  int by = blockIdx.y;
  bool m1path = (Bm != nullptr) && (by == 0);
  int r = (Bm != nullptr) ? by - 1 : by;
  const uint16_t* B = m1path ? Bm : (Bz + (size_t)r*16384);
  int arow = blockIdx.x*128 + wid*32 + l31;

  f16f acc[4];
  #pragma unroll
  for (int n = 0; n < 4; n++)
    #pragma unroll
    for (int i = 0; i < 16; i++) acc[n][i] = 0.f;

  #pragma unroll
  for (int ksI = 0; ksI < 8; ksI++){
    int k0 = ksI*16 + g*8;
    bf8_t a;
    if (ABF16){
      a = *(const bf8_t*)(Ab + (size_t)arow*128 + k0);
    } else {
      const float* ap = Af + (size_t)arow*128 + k0;
      float4 f0 = *(const float4*)ap;
      float4 f1 = *(const float4*)(ap + 4);
      union { uint16_t u[8]; bf8_t v; } ua;
      ua.u[0]=f2bf(f0.x); ua.u[1]=f2bf(f0.y); ua.u[2]=f2bf(f0.z); ua.u[3]=f2bf(f0.w);
      ua.u[4]=f2bf(f1.x); ua.u[5]=f2bf(f1.y); ua.u[6]=f2bf(f1.z); ua.u[7]=f2bf(f1.w);
      a = ua.v;
    }
    #pragma unroll
    for (int n = 0; n < 4; n++){
      bf8_t b = *(const bf8_t*)(B + (size_t)(n*32 + l31)*128 + k0);
      acc[n] = mfma32(a, b, acc[n]);
    }
  }
  #pragma unroll
  for (int n = 0; n < 4; n++){
    int colg = n*32 + l31;
    float bv = m1path ? bias[colg] : 0.f;
    #pragma unroll
    for (int v = 0; v < 16; v++){
      int rowl = (v&3) + 8*(v>>2) + 4*g;
      int rg = blockIdx.x*128 + wid*32 + rowl;   // mole index j
      float val = acc[n][v];
      if (m1path){
        m1out[(size_t)rg*128 + colg] = f2bf(fmaxf(val + bv, 0.f));
      } else {
        int pos = ((rg & 1) << 2) | ((rg & 7) >> 1);
        zpk[(size_t)(r*256 + (rg>>3))*1024 + colg*8 + pos] = f2bf(val);
      }
    }
  }
}

// ---- masked RGCN conv: 2-wave block, 128M x 128N, Z in double-buffered LDS ----
template<int NSLAB>
__global__ __launch_bounds__(128, 2) void k_conv(
    const uint32_t* __restrict__ levq, const float* __restrict__ inv,
    const uint16_t* __restrict__ zpk, const uint16_t* __restrict__ aroot,
    const uint16_t* __restrict__ rt, uint16_t* __restrict__ p16,
    float* __restrict__ p32){
  int tid = threadIdx.x;
  int lane = tid & 63, wid = tid >> 6;     // 2 waves
  int l31 = lane & 31, g = lane >> 5;
  int brow = blockIdx.x*128;
  int ks = blockIdx.y;                      // 0..15
  int kc0 = ks*16;                          // 16 8-k chunks per ks

  __shared__ uint16_t stage[2][10240];      // [buf][(r*2+ktsel)*1024 + d*8 + e]

  int row0 = brow + wid*64 + l31;
  int row1 = row0 + 32;

  // per-relation byte tables: byte (r+1) of the 8-byte pool = inv_r's lo/hi byte
  uint32_t tlo[2][5], thi[2][5];
  #pragma unroll
  for (int mt = 0; mt < 2; mt++){
    int rg = mt ? row1 : row0;
    #pragma unroll
    for (int r = 1; r <= 5; r++){
      uint32_t bits = (uint32_t)f2bf(inv[(size_t)rg*8 + r]);
      int sh = 8*((r+1)&3);
      tlo[mt][r-1] = (bits & 0xFFu) << sh;
      thi[mt][r-1] = (bits >> 8)    << sh;
    }
  }

  f16f acc[2][4];
  #pragma unroll
  for (int a0=0;a0<2;a0++)
    #pragma unroll
    for (int b0=0;b0<4;b0++)
      #pragma unroll
      for (int i=0;i<16;i++) acc[a0][b0][i]=0.f;

  // prologue: stage kk=0 (10 x dwordx4 per thread covers 20 KB/block)
  uint4 sreg[10];
  #pragma unroll
  for (int j = 0; j < 10; j++){
    int r = j >> 1, pc = j & 1;
    sreg[j] = *(const uint4*)(zpk + (size_t)(r*256 + kc0)*1024 + pc*1024 + tid*8);
  }
  #pragma unroll
  for (int j = 0; j < 10; j++)
    *(uint4*)(&stage[0][j*1024 + tid*8]) = sreg[j];

  // prefetch levq for kk=0
  uint32_t Lc0 = levq[(size_t)(kc0 + g)*NEPAD + row0];
  uint32_t Lc1 = levq[(size_t)(kc0 + g)*NEPAD + row1];
  __syncthreads();

  int buf = 0;
  for (int kk = 0; kk < 8; kk++){
    uint32_t Ln0, Ln1;
    if (kk < 7){
      int ktn = kc0 + (kk+1)*2;
      // issue next-tile global loads early (T14)
      #pragma unroll
      for (int j = 0; j < 10; j++){
        int r = j >> 1, pc = j & 1;
        sreg[j] = *(const uint4*)(zpk + (size_t)(r*256 + ktn)*1024 + pc*1024 + tid*8);
      }
      Ln0 = levq[(size_t)(ktn + g)*NEPAD + row0];
      Ln1 = levq[(size_t)(ktn + g)*NEPAD + row1];
    }
    // compute kk from stage[buf]
    uint32_t sx0 = Lc0 & 0x0F0F0F0Fu, sy0 = (Lc0 >> 4) & 0x0F0F0F0Fu;
    uint32_t sx1 = Lc1 & 0x0F0F0F0Fu, sy1 = (Lc1 >> 4) & 0x0F0F0F0Fu;
    const uint16_t* sb = &stage[buf][g*1024 + l31*8];
    #pragma unroll
    for (int r = 1; r <= 5; r++){
      bf8_t bn[4];
      #pragma unroll
      for (int nt = 0; nt < 4; nt++)
        bn[nt] = *(const bf8_t*)(sb + (r-1)*2048 + nt*256);
      #pragma unroll
      for (int mt = 0; mt < 2; mt++){
        uint32_t sx = mt ? sx1 : sx0;
        uint32_t sy = mt ? sy1 : sy0;
        uint32_t TL = tlo[mt][r-1], TH = thi[mt][r-1];
        uint32_t pl, ph, ql, qh;
        if (r < 3){   // table byte at index 2..3 -> low pool (src1)
          pl = __builtin_amdgcn_perm(0u, TL, sx);
          ph = __builtin_amdgcn_perm(0u, TH, sx);
          ql = __builtin_amdgcn_perm(0u, TL, sy);
          qh = __builtin_amdgcn_perm(0u, TH, sy);
        } else {      // table byte at index 4..6 -> high pool (src0)
          pl = __builtin_amdgcn_perm(TL, 0u, sx);
          ph = __builtin_amdgcn_perm(TH, 0u, sx);
          ql = __builtin_amdgcn_perm(TL, 0u, sy);
          qh = __builtin_amdgcn_perm(TH, 0u, sy);
        }
        union { uint32_t u[4]; bf8_t v; } A;
        A.u[0] = __builtin_amdgcn_perm(ph, pl, 0x05010400u);
        A.u[1] = __builtin_amdgcn_perm(ph, pl, 0x07030602u);
        A.u[2] = __builtin_amdgcn_perm(qh, ql, 0x05010400u);
        A.u[3] = __builtin_amdgcn_perm(qh, ql, 0x07030602u);
        acc[mt][0] = mfma32(A.v, bn[0], acc[mt][0]);
        acc[mt][1] = mfma32(A.v, bn[1], acc[mt][1]);
        acc[mt][2] = mfma32(A.v, bn[2], acc[mt][2]);
        acc[mt][3] = mfma32(A.v, bn[3], acc[mt][3]);
      }
    }
    if (kk < 7){
      // write-late: LDS write for kk+1, then barrier
      #pragma unroll
      for (int j = 0; j < 10; j++)
        *(uint4*)(&stage[buf^1][j*1024 + tid*8]) = sreg[j];
      __syncthreads();
      buf ^= 1;
      Lc0 = Ln0; Lc1 = Ln1;
    }
  }

  if (ks < 8){   // root-matmul k-chunk ks (16 of 128), balanced across first 8 ks
    int k0 = ks*16 + g*8;
    bf8_t a0 = *(const bf8_t*)(aroot + (size_t)row0*128 + k0);
    bf8_t a1 = *(const bf8_t*)(aroot + (size_t)row1*128 + k0);
    #pragma unroll
    for (int nt = 0; nt < 4; nt++){
      bf8_t rb = *(const bf8_t*)(rt + (size_t)(nt*32 + l31)*128 + k0);
      acc[0][nt] = mfma32(a0, rb, acc[0][nt]);
      acc[1][nt] = mfma32(a1, rb, acc[1][nt]);
    }
  }

  if (NSLAB == 16){
    uint16_t* dst = p16 + (size_t)ks*NEPAD*128;
    #pragma unroll
    for (int mt = 0; mt < 2; mt++){
      #pragma unroll
      for (int nt = 0; nt < 4; nt++){
        int colg = nt*32 + l31;
        #pragma unroll
        for (int v = 0; v < 16; v++){
          int rowl = (v&3) + 8*(v>>2) + 4*g;
          dst[(size_t)(brow + wid*64 + mt*32 + rowl)*128 + colg] = f2bf(acc[mt][nt][v]);
        }
      }
    }
  } else {
    #pragma unroll
    for (int mt = 0; mt < 2; mt++){
      #pragma unroll
      for (int nt = 0; nt < 4; nt++){
        int colg = nt*32 + l31;
        #pragma unroll
        for (int v = 0; v < 16; v++){
          int rowl = (v&3) + 8*(v>>2) + 4*g;
          unsafeAtomicAdd(&p32[(size_t)(brow + wid*64 + mt*32 + rowl)*128 + colg],
                          acc[mt][nt][v]);
        }
      }
    }
  }
}

// ---- reduce 16 bf16 slabs (or 1 f32 slab) + bias; C1: relu->bf16, else f32 ----
template<bool C1, bool S16>
__global__ __launch_bounds__(256) void k_red(
    const uint16_t* __restrict__ p16, const float* __restrict__ p32,
    const float* __restrict__ bias, uint16_t* __restrict__ e1bf,
    float* __restrict__ out){
  size_t idx8 = ((size_t)blockIdx.x*256 + threadIdx.x) * 8;   // < NEPAD*128
  int col = (int)(idx8 & 127);
  float s[8];
  #pragma unroll
  for (int j = 0; j < 8; j++) s[j] = bias[col + j];
  if (S16){
    #pragma unroll
    for (int sl = 0; sl < 16; sl++){
      union { uint4 q; uint16_t h[8]; } u;
      u.q = *(const uint4*)(p16 + (size_t)sl*NEPAD*128 + idx8);
      #pragma unroll
      for (int j = 0; j < 8; j++) s[j] += __uint_as_float(((uint32_t)u.h[j]) << 16);
    }
  } else {
    #pragma unroll
    for (int j = 0; j < 8; j += 4){
      float4 v = *(const float4*)(p32 + idx8 + j);
      s[j] += v.x; s[j+1] += v.y; s[j+2] += v.z; s[j+3] += v.w;
    }
  }
  if (C1){
    union { uint16_t u[8]; uint4 q; } ub;
    #pragma unroll
    for (int j = 0; j < 8; j++) ub.u[j] = f2bf(fmaxf(s[j], 0.f));
    *(uint4*)(e1bf + idx8) = ub.q;
  } else {
    if (idx8 < (size_t)NE*128){
      *(float4*)(out + idx8)     = make_float4(s[0], s[1], s[2], s[3]);
      *(float4*)(out + idx8 + 4) = make_float4(s[4], s[5], s[6], s[7]);
    }
  }
}

extern "C" void kernel_launch(void* const* d_in, const int* in_sizes, int n_in,
                              void* d_out, int out_size, void* d_ws, size_t ws_size,
                              hipStream_t stream){
  const float* xe  = (const float*)d_in[0];
  const float* xm  = (const float*)d_in[1];
  const float* w   = (const float*)d_in[2];
  const float* W1  = (const float*)d_in[3];
  const float* r1  = (const float*)d_in[4];
  const float* b1  = (const float*)d_in[5];
  const float* W2  = (const float*)d_in[6];
  const float* r2  = (const float*)d_in[7];
  const float* b2  = (const float*)d_in[8];
  float* out = (float*)d_out;
  char* ws = (char*)d_ws;

  constexpr size_t OFF_INV  = 0;                                   // NEPAD*8*4
  constexpr size_t OFF_XEBF = OFF_INV  + (size_t)NEPAD*8*4;        // NEPAD*128*2 (also e1bf)
  constexpr size_t OFF_M1   = OFF_XEBF + (size_t)NEPAD*128*2;      // NM*128*2
  constexpr size_t OFF_Z1   = OFF_M1   + (size_t)NM*128*2;         // 5*NM*128*2
  constexpr size_t OFF_Z2   = OFF_Z1   + (size_t)5*NM*128*2;       // 5*NM*128*2
  constexpr size_t OFF_R1T  = OFF_Z2   + (size_t)5*NM*128*2;
  constexpr size_t OFF_R2T  = OFF_R1T  + 128*128*2;
  constexpr size_t OFF_W1T  = OFF_R2T  + 128*128*2;
  constexpr size_t OFF_W2T  = OFF_W1T  + (size_t)5*128*128*2;
  constexpr size_t OFF_LEVQ = OFF_W2T  + (size_t)5*128*128*2;      // 256*NEPAD*4 (~10.4MB)
  constexpr size_t OFF_PART = OFF_LEVQ + (size_t)256*NEPAD*4;
  constexpr size_t SLAB16   = (size_t)NEPAD*128*2;                 // 2.59 MB bf16 slab
  constexpr size_t NEED_A   = OFF_PART + 16*SLAB16;                // ~60.8 MB
  constexpr size_t SLABF    = (size_t)NEPAD*128*4;                 // f32 fallback slab

  float*    inv  = (float*)   (ws + OFF_INV);
  uint16_t* xebf = (uint16_t*)(ws + OFF_XEBF);
  uint16_t* m1   = (uint16_t*)(ws + OFF_M1);
  uint16_t* z1   = (uint16_t*)(ws + OFF_Z1);
  uint16_t* z2   = (uint16_t*)(ws + OFF_Z2);
  uint16_t* r1t  = (uint16_t*)(ws + OFF_R1T);
  uint16_t* r2t  = (uint16_t*)(ws + OFF_R2T);
  uint16_t* w1t  = (uint16_t*)(ws + OFF_W1T);
  uint16_t* w2t  = (uint16_t*)(ws + OFF_W2T);
  uint32_t* levq = (uint32_t*)(ws + OFF_LEVQ);
  uint16_t* p16  = (uint16_t*)(ws + OFF_PART);
  float*    p32  = (float*)   (ws + OFF_PART);

  bool tierA = (ws_size >= NEED_A);

  hipLaunchKernelGGL(k_prep, dim3(768), dim3(256), 0, stream,
                     r1, r2, W1, W2, r1t, r2t, w1t, w2t);
  hipLaunchKernelGGL(k_lev, dim3(NEPAD/32), dim3(256), 0, stream,
                     w, xe, levq, inv, xebf);
  // y=0: m1 = relu(xm@root1+b1); y=1..5: z1[y-1] = pack(xm@W1[y-1])
  hipLaunchKernelGGL((k_gemm<false>), dim3(16,6), dim3(256), 0, stream,
                     xm, (const uint16_t*)nullptr, r1t, w1t, b1, m1, z1);
  // z2[r] = pack(m1@W2[r])
  hipLaunchKernelGGL((k_gemm<true>), dim3(16,5), dim3(256), 0, stream,
                     (const float*)nullptr, m1, (const uint16_t*)nullptr, w2t,
                     (const float*)nullptr, (uint16_t*)nullptr, z2);
  if (tierA){
    hipLaunchKernelGGL((k_conv<16>), dim3(NEPAD/128, KSPLIT), dim3(128), 0, stream,
                       levq, inv, z1, xebf, r1t, p16, (float*)nullptr);
    hipLaunchKernelGGL((k_red<true,true>), dim3(NEPAD*128/2048), dim3(256), 0, stream,
                       p16, (const float*)nullptr, b1, xebf, (float*)nullptr);
    hipLaunchKernelGGL((k_conv<16>), dim3(NEPAD/128, KSPLIT), dim3(128), 0, stream,
                       levq, inv, z2, xebf, r2t, p16, (float*)nullptr);
    hipLaunchKernelGGL((k_red<false,true>), dim3(NEPAD*128/2048), dim3(256), 0, stream,
                       p16, (const float*)nullptr, b2, (uint16_t*)nullptr, out);
  } else {
    hipMemsetAsync(p32, 0, SLABF, stream);
    hipLaunchKernelGGL((k_conv<1>), dim3(NEPAD/128, KSPLIT), dim3(128), 0, stream,
                       levq, inv, z1, xebf, r1t, (uint16_t*)nullptr, p32);
    hipLaunchKernelGGL((k_red<true,false>), dim3(NEPAD*128/2048), dim3(256), 0, stream,
                       (const uint16_t*)nullptr, p32, b1, xebf, (float*)nullptr);
    hipMemsetAsync(p32, 0, SLABF, stream);
    hipLaunchKernelGGL((k_conv<1>), dim3(NEPAD/128, KSPLIT), dim3(128), 0, stream,
                       levq, inv, z2, xebf, r2t, (uint16_t*)nullptr, p32);
    hipLaunchKernelGGL((k_red<false,false>), dim3(NEPAD*128/2048), dim3(256), 0, stream,
                       (const uint16_t*)nullptr, p32, b2, (uint16_t*)nullptr, out);
  }
}

// Round 7
// 132.636 us; speedup vs baseline: 1.7337x; 1.0406x over previous
//
#include <hip/hip_runtime.h>
#include <stdint.h>

// hetero_effect_graph: 2-layer RGCN over dense level-partitioned bipartite graph.
// 6 dispatches:
//  k_init : [bx<48] transpose+bf16 weights; [bx>=48] lev nibbles k-major, inv, xe->bf16
//  k_gemm : m1 = relu(xm@root1+b1); z1[r] = pack(xm@W1[r])  (k-order [0,2,4,6,1,3,5,7])
//  k_conv<FUSE=1> : conv1 partial slabs (BM=64, 2 waves split N, Z double-buffered in
//           LDS, perm-built A) + 160 fused blocks computing z2[r] = pack(m1@W2[r])
//  k_red<1> : e1 = relu(sum_8 slabs + b1) -> bf16 (xebf buffer)
//  k_conv<FUSE=0> : conv2 partial slabs
//  k_red<0> : out = sum_8 slabs + b2 (f32)

#define NE 10000
#define NM 2048
#define NEPAD 10112   // 79 * 128
#define MB64 158      // NEPAD / 64
#define KSPLIT 8

typedef short bf8_t __attribute__((ext_vector_type(8)));
typedef float f16f  __attribute__((ext_vector_type(16)));

__device__ __forceinline__ uint16_t f2bf(float f){
  uint32_t u = __float_as_uint(f);
  u += 0x7FFFu + ((u >> 16) & 1u);
  return (uint16_t)(u >> 16);
}

__device__ __forceinline__ f16f mfma32(bf8_t a, bf8_t b, f16f c){
  return __builtin_amdgcn_mfma_f32_32x32x16_bf16(a, b, c, 0, 0, 0);
}

// ---- fused: weight prep (48 blocks) + lev/inv/xebf (316 blocks) ----
__global__ __launch_bounds__(256) void k_init(
    const float* __restrict__ root1, const float* __restrict__ root2,
    const float* __restrict__ W1, const float* __restrict__ W2,
    uint16_t* __restrict__ r1t, uint16_t* __restrict__ r2t,
    uint16_t* __restrict__ w1t, uint16_t* __restrict__ w2t,
    const float* __restrict__ w, const float* __restrict__ xe,
    uint32_t* __restrict__ levq, float* __restrict__ inv,
    uint16_t* __restrict__ xebf){
  int t = threadIdx.x;
  if (blockIdx.x < 48){               // ---- weight transpose+convert ----
    int idx = blockIdx.x*4096 + t;
    #pragma unroll
    for (int it = 0; it < 16; it++, idx += 256){
      int slab = idx >> 14;
      int pos  = idx & 16383;
      int d = pos >> 7, k = pos & 127;
      float v; uint16_t* dst;
      if (slab == 0)      { v = root1[k*128 + d]; dst = r1t; }
      else if (slab == 1) { v = root2[k*128 + d]; dst = r2t; }
      else if (slab < 7)  { v = W1[(slab-1)*16384 + k*128 + d]; dst = w1t + (slab-2)*16384; }
      else                { v = W2[(slab-6)*16384 + k*128 + d]; dst = w2t + (slab-7)*16384; }
      dst[pos] = f2bf(v);
    }
    return;
  }
  // ---- lev part: 32 rows per block ----
  int brow = (blockIdx.x - 48) * 32;
  int rloc = t >> 3, p = t & 7;          // 8 threads per row
  int row = brow + rloc;
  bool active = row < NE;
  const float* wr = w + (size_t)row * NM;
  unsigned long long cnt = 0ull;         // 5 x 12-bit packed relation counters
  __shared__ uint32_t tile[32][33];

  for (int cp = 0; cp < 8; cp++){        // 8 column-panels of 256 cols
    uint32_t packs[4];
    #pragma unroll
    for (int q = 0; q < 4; q++){
      int gck = cp*32 + p + 8*q;         // global 8-col chunk
      uint32_t L = 0;
      if (active){
        const float4* f = (const float4*)(wr + gck*8);
        float4 f0 = f[0], f1 = f[1];
        float wv[8] = {f0.x,f0.y,f0.z,f0.w, f1.x,f1.y,f1.z,f1.w};
        #pragma unroll
        for (int e = 0; e < 8; e++){
          int s = (int)ceilf(wv[e]*6.0f);          // lev+1 in 1..6
          if (s >= 2) cnt += 1ull << (12*(s-2));   // relations 1..5
          L |= (uint32_t)s << (4*e);
        }
      }
      packs[q] = L;
    }
    __syncthreads();
    #pragma unroll
    for (int q = 0; q < 4; q++) tile[p + 8*q][rloc] = packs[q];
    __syncthreads();
    int ckk = t >> 3;
    int r4  = (t & 7) * 4;
    size_t base = (size_t)(cp*32 + ckk) * NEPAD + brow + r4;
    *(uint4*)(levq + base) = make_uint4(tile[ckk][r4], tile[ckk][r4+1],
                                        tile[ckk][r4+2], tile[ckk][r4+3]);
  }

  unsigned long long c = cnt;
  c += __shfl_xor(c, 1);
  c += __shfl_xor(c, 2);
  c += __shfl_xor(c, 4);
  if (p == 0 && row < NEPAD){
    if (active){
      inv[row*8 + 0] = 0.f; inv[row*8 + 6] = 0.f; inv[row*8 + 7] = 0.f;
      #pragma unroll
      for (int r = 1; r <= 5; r++){
        uint32_t cc = (uint32_t)((c >> (12*(r-1))) & 0xFFFull);
        inv[row*8 + r] = cc ? 1.0f/(float)cc : 0.f;
      }
    } else {
      #pragma unroll
      for (int i = 0; i < 8; i++) inv[row*8 + i] = 0.f;
    }
  }

  int f0i = p * 16;
  if (active){
    union { uint16_t u[16]; uint4 q[2]; } ub;
    #pragma unroll
    for (int j = 0; j < 4; j++){
      float4 a = *(const float4*)(xe + (size_t)row*128 + f0i + j*4);
      ub.u[j*4+0]=f2bf(a.x); ub.u[j*4+1]=f2bf(a.y); ub.u[j*4+2]=f2bf(a.z); ub.u[j*4+3]=f2bf(a.w);
    }
    *(uint4*)(xebf + (size_t)row*128 + f0i)     = ub.q[0];
    *(uint4*)(xebf + (size_t)row*128 + f0i + 8) = ub.q[1];
  } else if (row < NEPAD){
    uint4 z = make_uint4(0,0,0,0);
    *(uint4*)(xebf + (size_t)row*128 + f0i)     = z;
    *(uint4*)(xebf + (size_t)row*128 + f0i + 8) = z;
  }
}

// ---- small GEMM [2048x128]@[128x128]; y=0: m1 (bias+relu); y>0: z1 pack ----
__global__ __launch_bounds__(256) void k_gemm(
    const float* __restrict__ Af, const uint16_t* __restrict__ Bm,
    const uint16_t* __restrict__ Bz, const float* __restrict__ bias,
    uint16_t* __restrict__ m1out, uint16_t* __restrict__ zpk){
  int tid = threadIdx.x;
  int lane = tid & 63, wid = tid >> 6;
  int l31 = lane & 31, g = lane >> 5;
  int by = blockIdx.y;
  bool m1path = (by == 0);
  int r = by - 1;
  const uint16_t* B = m1path ? Bm : (Bz + (size_t)r*16384);
  int arow = blockIdx.x*128 + wid*32 + l31;

  f16f acc[4];
  #pragma unroll
  for (int n = 0; n < 4; n++)
    #pragma unroll
    for (int i = 0; i < 16; i++) acc[n][i] = 0.f;

  #pragma unroll
  for (int ksI = 0; ksI < 8; ksI++){
    int k0 = ksI*16 + g*8;
    const float* ap = Af + (size_t)arow*128 + k0;
    float4 f0 = *(const float4*)ap;
    float4 f1 = *(const float4*)(ap + 4);
    union { uint16_t u[8]; bf8_t v; } ua;
    ua.u[0]=f2bf(f0.x); ua.u[1]=f2bf(f0.y); ua.u[2]=f2bf(f0.z); ua.u[3]=f2bf(f0.w);
    ua.u[4]=f2bf(f1.x); ua.u[5]=f2bf(f1.y); ua.u[6]=f2bf(f1.z); ua.u[7]=f2bf(f1.w);
    #pragma unroll
    for (int n = 0; n < 4; n++){
      bf8_t b = *(const bf8_t*)(B + (size_t)(n*32 + l31)*128 + k0);
      acc[n] = mfma32(ua.v, b, acc[n]);
    }
  }
  #pragma unroll
  for (int n = 0; n < 4; n++){
    int colg = n*32 + l31;
    float bv = m1path ? bias[colg] : 0.f;
    #pragma unroll
    for (int v = 0; v < 16; v++){
      int rowl = (v&3) + 8*(v>>2) + 4*g;
      int rg = blockIdx.x*128 + wid*32 + rowl;   // mole index j
      float val = acc[n][v];
      if (m1path){
        m1out[(size_t)rg*128 + colg] = f2bf(fmaxf(val + bv, 0.f));
      } else {
        int pos = ((rg & 1) << 2) | ((rg & 7) >> 1);
        zpk[(size_t)(r*256 + (rg>>3))*1024 + colg*8 + pos] = f2bf(val);
      }
    }
  }
}

// ---- masked RGCN conv: BM=64, 2 waves split N, Z dbuf in LDS; FUSE: +z2 gemm ----
template<int NSLAB, bool FUSE>
__global__ __launch_bounds__(128, 2) void k_conv(
    const uint32_t* __restrict__ levq, const float* __restrict__ inv,
    const uint16_t* __restrict__ zpk, const uint16_t* __restrict__ aroot,
    const uint16_t* __restrict__ rt,
    const uint16_t* __restrict__ gA, const uint16_t* __restrict__ gB,
    uint16_t* __restrict__ gOut,
    uint16_t* __restrict__ p16, float* __restrict__ p32){
  int tid = threadIdx.x;
  int lane = tid & 63, wid = tid >> 6;     // 2 waves
  int l31 = lane & 31, g = lane >> 5;

  if (FUSE && blockIdx.x >= MB64){
    // ---- fused z2 gemm: 160 blocks x 64 rows: z2[r] = pack(m1 @ W2[r]) ----
    int b = blockIdx.y*20 + (blockIdx.x - MB64);   // 0..159
    int r = b >> 5;                                 // 0..4
    int rowb = (b & 31)*64 + wid*32;
    int arow = rowb + l31;
    const uint16_t* B = gB + (size_t)r*16384;
    f16f acc[4];
    #pragma unroll
    for (int n = 0; n < 4; n++)
      #pragma unroll
      for (int i = 0; i < 16; i++) acc[n][i] = 0.f;
    #pragma unroll
    for (int ksI = 0; ksI < 8; ksI++){
      int k0 = ksI*16 + g*8;
      bf8_t a = *(const bf8_t*)(gA + (size_t)arow*128 + k0);
      #pragma unroll
      for (int n = 0; n < 4; n++){
        bf8_t bb = *(const bf8_t*)(B + (size_t)(n*32 + l31)*128 + k0);
        acc[n] = mfma32(a, bb, acc[n]);
      }
    }
    #pragma unroll
    for (int n = 0; n < 4; n++){
      int colg = n*32 + l31;
      #pragma unroll
      for (int v = 0; v < 16; v++){
        int rowl = (v&3) + 8*(v>>2) + 4*g;
        int rg = rowb + rowl;
        int pos = ((rg & 1) << 2) | ((rg & 7) >> 1);
        gOut[(size_t)(r*256 + (rg>>3))*1024 + colg*8 + pos] = f2bf(acc[n][v]);
      }
    }
    return;
  }

  // ---- conv part ----
  int brow = blockIdx.x*64;
  int ks = blockIdx.y;                      // 0..7
  int kc0 = ks*32;                          // 32 8-k chunks per ks
  int wn = wid;                             // this wave's 64-col half

  __shared__ uint16_t stage[2][10240];      // [(r*2+pc)*1024 + d*8 + e]

  int row0 = brow + l31;
  int row1 = row0 + 32;

  uint32_t tlo[2][5], thi[2][5];
  #pragma unroll
  for (int mt = 0; mt < 2; mt++){
    int rg = mt ? row1 : row0;
    #pragma unroll
    for (int r = 1; r <= 5; r++){
      uint32_t bits = (uint32_t)f2bf(inv[(size_t)rg*8 + r]);
      int sh = 8*((r+1)&3);
      tlo[mt][r-1] = (bits & 0xFFu) << sh;
      thi[mt][r-1] = (bits >> 8)    << sh;
    }
  }

  f16f acc[2][2];
  #pragma unroll
  for (int a0=0;a0<2;a0++)
    #pragma unroll
    for (int b0=0;b0<2;b0++)
      #pragma unroll
      for (int i=0;i<16;i++) acc[a0][b0][i]=0.f;

  // prologue: stage kk=0 (10 x dwordx4 per thread = 20 KB/block)
  uint4 sreg[10];
  #pragma unroll
  for (int j = 0; j < 10; j++){
    int r = j >> 1, pc = j & 1;
    sreg[j] = *(const uint4*)(zpk + (size_t)(r*256 + kc0 + pc)*1024 + tid*8);
  }
  #pragma unroll
  for (int j = 0; j < 10; j++)
    *(uint4*)(&stage[0][j*1024 + tid*8]) = sreg[j];

  uint32_t Lc0 = levq[(size_t)(kc0 + g)*NEPAD + row0];
  uint32_t Lc1 = levq[(size_t)(kc0 + g)*NEPAD + row1];
  __syncthreads();

  int buf = 0;
  for (int kk = 0; kk < 16; kk++){
    uint32_t Ln0, Ln1;
    if (kk < 15){
      int ktn = kc0 + (kk+1)*2;
      #pragma unroll
      for (int j = 0; j < 10; j++){
        int r = j >> 1, pc = j & 1;
        sreg[j] = *(const uint4*)(zpk + (size_t)(r*256 + ktn + pc)*1024 + tid*8);
      }
      Ln0 = levq[(size_t)(ktn + g)*NEPAD + row0];
      Ln1 = levq[(size_t)(ktn + g)*NEPAD + row1];
    }
    uint32_t sx0 = Lc0 & 0x0F0F0F0Fu, sy0 = (Lc0 >> 4) & 0x0F0F0F0Fu;
    uint32_t sx1 = Lc1 & 0x0F0F0F0Fu, sy1 = (Lc1 >> 4) & 0x0F0F0F0Fu;
    const uint16_t* sb = &stage[buf][g*1024 + l31*8];
    #pragma unroll
    for (int r = 1; r <= 5; r++){
      bf8_t bn0 = *(const bf8_t*)(sb + (r-1)*2048 + (wn*2  )*256);
      bf8_t bn1 = *(const bf8_t*)(sb + (r-1)*2048 + (wn*2+1)*256);
      #pragma unroll
      for (int mt = 0; mt < 2; mt++){
        uint32_t sx = mt ? sx1 : sx0;
        uint32_t sy = mt ? sy1 : sy0;
        uint32_t TL = tlo[mt][r-1], TH = thi[mt][r-1];
        uint32_t pl, ph, ql, qh;
        if (r < 3){   // table byte at index 2..3 -> low pool (src1)
          pl = __builtin_amdgcn_perm(0u, TL, sx);
          ph = __builtin_amdgcn_perm(0u, TH, sx);
          ql = __builtin_amdgcn_perm(0u, TL, sy);
          qh = __builtin_amdgcn_perm(0u, TH, sy);
        } else {      // table byte at index 4..6 -> high pool (src0)
          pl = __builtin_amdgcn_perm(TL, 0u, sx);
          ph = __builtin_amdgcn_perm(TH, 0u, sx);
          ql = __builtin_amdgcn_perm(TL, 0u, sy);
          qh = __builtin_amdgcn_perm(TH, 0u, sy);
        }
        union { uint32_t u[4]; bf8_t v; } A;
        A.u[0] = __builtin_amdgcn_perm(ph, pl, 0x05010400u);
        A.u[1] = __builtin_amdgcn_perm(ph, pl, 0x07030602u);
        A.u[2] = __builtin_amdgcn_perm(qh, ql, 0x05010400u);
        A.u[3] = __builtin_amdgcn_perm(qh, ql, 0x07030602u);
        acc[mt][0] = mfma32(A.v, bn0, acc[mt][0]);
        acc[mt][1] = mfma32(A.v, bn1, acc[mt][1]);
      }
    }
    if (kk < 15){
      #pragma unroll
      for (int j = 0; j < 10; j++)
        *(uint4*)(&stage[buf^1][j*1024 + tid*8]) = sreg[j];
      __syncthreads();
      buf ^= 1;
      Lc0 = Ln0; Lc1 = Ln1;
    }
  }

  {  // root-matmul k-chunk ks (16 of 128) — exactly balanced over ks 0..7
    int k0 = ks*16 + g*8;
    bf8_t a0 = *(const bf8_t*)(aroot + (size_t)row0*128 + k0);
    bf8_t a1 = *(const bf8_t*)(aroot + (size_t)row1*128 + k0);
    #pragma unroll
    for (int nt = 0; nt < 2; nt++){
      bf8_t rb = *(const bf8_t*)(rt + (size_t)((wn*2+nt)*32 + l31)*128 + k0);
      acc[0][nt] = mfma32(a0, rb, acc[0][nt]);
      acc[1][nt] = mfma32(a1, rb, acc[1][nt]);
    }
  }

  if (NSLAB == 8){
    uint16_t* dst = p16 + (size_t)ks*NEPAD*128;
    #pragma unroll
    for (int mt = 0; mt < 2; mt++){
      #pragma unroll
      for (int nt = 0; nt < 2; nt++){
        int colg = (wn*2+nt)*32 + l31;
        #pragma unroll
        for (int v = 0; v < 16; v++){
          int rowl = (v&3) + 8*(v>>2) + 4*g;
          dst[(size_t)(brow + mt*32 + rowl)*128 + colg] = f2bf(acc[mt][nt][v]);
        }
      }
    }
  } else {
    #pragma unroll
    for (int mt = 0; mt < 2; mt++){
      #pragma unroll
      for (int nt = 0; nt < 2; nt++){
        int colg = (wn*2+nt)*32 + l31;
        #pragma unroll
        for (int v = 0; v < 16; v++){
          int rowl = (v&3) + 8*(v>>2) + 4*g;
          unsafeAtomicAdd(&p32[(size_t)(brow + mt*32 + rowl)*128 + colg],
                          acc[mt][nt][v]);
        }
      }
    }
  }
}

// ---- reduce 8 bf16 slabs (or 1 f32 slab) + bias; C1: relu->bf16, else f32 ----
template<bool C1, bool S16>
__global__ __launch_bounds__(256) void k_red(
    const uint16_t* __restrict__ p16, const float* __restrict__ p32,
    const float* __restrict__ bias, uint16_t* __restrict__ e1bf,
    float* __restrict__ out){
  size_t idx8 = ((size_t)blockIdx.x*256 + threadIdx.x) * 8;   // < NEPAD*128
  int col = (int)(idx8 & 127);
  float s[8];
  #pragma unroll
  for (int j = 0; j < 8; j++) s[j] = bias[col + j];
  if (S16){
    #pragma unroll
    for (int sl = 0; sl < 8; sl++){
      union { uint4 q; uint16_t h[8]; } u;
      u.q = *(const uint4*)(p16 + (size_t)sl*NEPAD*128 + idx8);
      #pragma unroll
      for (int j = 0; j < 8; j++) s[j] += __uint_as_float(((uint32_t)u.h[j]) << 16);
    }
  } else {
    #pragma unroll
    for (int j = 0; j < 8; j += 4){
      float4 v = *(const float4*)(p32 + idx8 + j);
      s[j] += v.x; s[j+1] += v.y; s[j+2] += v.z; s[j+3] += v.w;
    }
  }
  if (C1){
    union { uint16_t u[8]; uint4 q; } ub;
    #pragma unroll
    for (int j = 0; j < 8; j++) ub.u[j] = f2bf(fmaxf(s[j], 0.f));
    *(uint4*)(e1bf + idx8) = ub.q;
  } else {
    if (idx8 < (size_t)NE*128){
      *(float4*)(out + idx8)     = make_float4(s[0], s[1], s[2], s[3]);
      *(float4*)(out + idx8 + 4) = make_float4(s[4], s[5], s[6], s[7]);
    }
  }
}

extern "C" void kernel_launch(void* const* d_in, const int* in_sizes, int n_in,
                              void* d_out, int out_size, void* d_ws, size_t ws_size,
                              hipStream_t stream){
  const float* xe  = (const float*)d_in[0];
  const float* xm  = (const float*)d_in[1];
  const float* w   = (const float*)d_in[2];
  const float* W1  = (const float*)d_in[3];
  const float* r1  = (const float*)d_in[4];
  const float* b1  = (const float*)d_in[5];
  const float* W2  = (const float*)d_in[6];
  const float* r2  = (const float*)d_in[7];
  const float* b2  = (const float*)d_in[8];
  float* out = (float*)d_out;
  char* ws = (char*)d_ws;

  constexpr size_t OFF_INV  = 0;                                   // NEPAD*8*4
  constexpr size_t OFF_XEBF = OFF_INV  + (size_t)NEPAD*8*4;        // NEPAD*128*2 (also e1bf)
  constexpr size_t OFF_M1   = OFF_XEBF + (size_t)NEPAD*128*2;      // NM*128*2
  constexpr size_t OFF_Z1   = OFF_M1   + (size_t)NM*128*2;         // 5*NM*128*2
  constexpr size_t OFF_Z2   = OFF_Z1   + (size_t)5*NM*128*2;       // 5*NM*128*2
  constexpr size_t OFF_R1T  = OFF_Z2   + (size_t)5*NM*128*2;
  constexpr size_t OFF_R2T  = OFF_R1T  + 128*128*2;
  constexpr size_t OFF_W1T  = OFF_R2T  + 128*128*2;
  constexpr size_t OFF_W2T  = OFF_W1T  + (size_t)5*128*128*2;
  constexpr size_t OFF_LEVQ = OFF_W2T  + (size_t)5*128*128*2;      // 256*NEPAD*4 (~10.4MB)
  constexpr size_t OFF_PART = OFF_LEVQ + (size_t)256*NEPAD*4;
  constexpr size_t SLAB16   = (size_t)NEPAD*128*2;                 // 2.59 MB bf16 slab
  constexpr size_t NEED_A   = OFF_PART + 8*SLAB16;                 // ~42 MB
  constexpr size_t SLABF    = (size_t)NEPAD*128*4;                 // f32 fallback slab

  float*    inv  = (float*)   (ws + OFF_INV);
  uint16_t* xebf = (uint16_t*)(ws + OFF_XEBF);
  uint16_t* m1   = (uint16_t*)(ws + OFF_M1);
  uint16_t* z1   = (uint16_t*)(ws + OFF_Z1);
  uint16_t* z2   = (uint16_t*)(ws + OFF_Z2);
  uint16_t* r1t  = (uint16_t*)(ws + OFF_R1T);
  uint16_t* r2t  = (uint16_t*)(ws + OFF_R2T);
  uint16_t* w1t  = (uint16_t*)(ws + OFF_W1T);
  uint16_t* w2t  = (uint16_t*)(ws + OFF_W2T);
  uint32_t* levq = (uint32_t*)(ws + OFF_LEVQ);
  uint16_t* p16  = (uint16_t*)(ws + OFF_PART);
  float*    p32  = (float*)   (ws + OFF_PART);

  bool tierA = (ws_size >= NEED_A);

  // prep (48 blocks) + lev (316 blocks)
  hipLaunchKernelGGL(k_init, dim3(48 + NEPAD/32), dim3(256), 0, stream,
                     r1, r2, W1, W2, r1t, r2t, w1t, w2t,
                     w, xe, levq, inv, xebf);
  // y=0: m1 = relu(xm@root1+b1); y=1..5: z1[y-1] = pack(xm@W1[y-1])
  hipLaunchKernelGGL(k_gemm, dim3(16,6), dim3(256), 0, stream,
                     xm, r1t, w1t, b1, m1, z1);
  if (tierA){
    // conv1 partials + fused z2 gemm
    hipLaunchKernelGGL((k_conv<8,true>), dim3(MB64 + 20, KSPLIT), dim3(128), 0, stream,
                       levq, inv, z1, xebf, r1t, m1, w2t, z2, p16, (float*)nullptr);
    hipLaunchKernelGGL((k_red<true,true>), dim3(NEPAD*128/2048), dim3(256), 0, stream,
                       p16, (const float*)nullptr, b1, xebf, (float*)nullptr);
    hipLaunchKernelGGL((k_conv<8,false>), dim3(MB64, KSPLIT), dim3(128), 0, stream,
                       levq, inv, z2, xebf, r2t,
                       (const uint16_t*)nullptr, (const uint16_t*)nullptr,
                       (uint16_t*)nullptr, p16, (float*)nullptr);
    hipLaunchKernelGGL((k_red<false,true>), dim3(NEPAD*128/2048), dim3(256), 0, stream,
                       p16, (const float*)nullptr, b2, (uint16_t*)nullptr, out);
  } else {
    hipMemsetAsync(p32, 0, SLABF, stream);
    hipLaunchKernelGGL((k_conv<1,true>), dim3(MB64 + 20, KSPLIT), dim3(128), 0, stream,
                       levq, inv, z1, xebf, r1t, m1, w2t, z2,
                       (uint16_t*)nullptr, p32);
    hipLaunchKernelGGL((k_red<true,false>), dim3(NEPAD*128/2048), dim3(256), 0, stream,
                       (const uint16_t*)nullptr, p32, b1, xebf, (float*)nullptr);
    hipMemsetAsync(p32, 0, SLABF, stream);
    hipLaunchKernelGGL((k_conv<1,false>), dim3(MB64, KSPLIT), dim3(128), 0, stream,
                       levq, inv, z2, xebf, r2t,
                       (const uint16_t*)nullptr, (const uint16_t*)nullptr,
                       (uint16_t*)nullptr, (uint16_t*)nullptr, p32);
    hipLaunchKernelGGL((k_red<false,false>), dim3(NEPAD*128/2048), dim3(256), 0, stream,
                       (const uint16_t*)nullptr, p32, b2, (uint16_t*)nullptr, out);
  }
}

// Round 8
// 121.133 us; speedup vs baseline: 1.8984x; 1.0950x over previous
//
#include <hip/hip_runtime.h>
#include <stdint.h>

// hetero_effect_graph: 2-layer RGCN over dense level-partitioned bipartite graph.
// 6 dispatches:
//  k_init : [bx<48] transpose+bf16 weights; [bx>=48] lev nibbles k-major, inv, xe->bf16
//  k_gemm : m1 = relu(xm@root1+b1); z1[r] = pack(xm@W1[r])  (k-order [0,2,4,6,1,3,5,7])
//  k_conv<FUSE=1> : conv1 partial slabs (BM=128, 4 waves x 32 rows x full-N,
//           Z double-buffered in LDS, perm-built A, 4 MFMA per build) + 80 fused
//           blocks computing z2[r] = pack(m1@W2[r])
//  k_red<1> : e1 = relu(sum_8 slabs + b1) -> bf16 (xebf buffer)
//  k_conv<FUSE=0> : conv2 partial slabs
//  k_red<0> : out = sum_8 slabs + b2 (f32)

#define NE 10000
#define NM 2048
#define NEPAD 10112   // 79 * 128
#define MB128 79      // NEPAD / 128
#define KSPLIT 8

typedef short bf8_t __attribute__((ext_vector_type(8)));
typedef float f16f  __attribute__((ext_vector_type(16)));

__device__ __forceinline__ uint16_t f2bf(float f){
  uint32_t u = __float_as_uint(f);
  u += 0x7FFFu + ((u >> 16) & 1u);
  return (uint16_t)(u >> 16);
}

__device__ __forceinline__ f16f mfma32(bf8_t a, bf8_t b, f16f c){
  return __builtin_amdgcn_mfma_f32_32x32x16_bf16(a, b, c, 0, 0, 0);
}

// ---- fused: weight prep (48 blocks) + lev/inv/xebf (316 blocks) ----
__global__ __launch_bounds__(256) void k_init(
    const float* __restrict__ root1, const float* __restrict__ root2,
    const float* __restrict__ W1, const float* __restrict__ W2,
    uint16_t* __restrict__ r1t, uint16_t* __restrict__ r2t,
    uint16_t* __restrict__ w1t, uint16_t* __restrict__ w2t,
    const float* __restrict__ w, const float* __restrict__ xe,
    uint32_t* __restrict__ levq, float* __restrict__ inv,
    uint16_t* __restrict__ xebf){
  int t = threadIdx.x;
  if (blockIdx.x < 48){               // ---- weight transpose+convert ----
    int idx = blockIdx.x*4096 + t;
    #pragma unroll
    for (int it = 0; it < 16; it++, idx += 256){
      int slab = idx >> 14;
      int pos  = idx & 16383;
      int d = pos >> 7, k = pos & 127;
      float v; uint16_t* dst;
      if (slab == 0)      { v = root1[k*128 + d]; dst = r1t; }
      else if (slab == 1) { v = root2[k*128 + d]; dst = r2t; }
      else if (slab < 7)  { v = W1[(slab-1)*16384 + k*128 + d]; dst = w1t + (slab-2)*16384; }
      else                { v = W2[(slab-6)*16384 + k*128 + d]; dst = w2t + (slab-7)*16384; }
      dst[pos] = f2bf(v);
    }
    return;
  }
  // ---- lev part: 32 rows per block ----
  int brow = (blockIdx.x - 48) * 32;
  int rloc = t >> 3, p = t & 7;          // 8 threads per row
  int row = brow + rloc;
  bool active = row < NE;
  const float* wr = w + (size_t)row * NM;
  unsigned long long cnt = 0ull;         // 5 x 12-bit packed relation counters
  __shared__ uint32_t tile[32][33];

  for (int cp = 0; cp < 8; cp++){        // 8 column-panels of 256 cols
    uint32_t packs[4];
    #pragma unroll
    for (int q = 0; q < 4; q++){
      int gck = cp*32 + p + 8*q;         // global 8-col chunk
      uint32_t L = 0;
      if (active){
        const float4* f = (const float4*)(wr + gck*8);
        float4 f0 = f[0], f1 = f[1];
        float wv[8] = {f0.x,f0.y,f0.z,f0.w, f1.x,f1.y,f1.z,f1.w};
        #pragma unroll
        for (int e = 0; e < 8; e++){
          int s = (int)ceilf(wv[e]*6.0f);          // lev+1 in 1..6
          if (s >= 2) cnt += 1ull << (12*(s-2));   // relations 1..5
          L |= (uint32_t)s << (4*e);
        }
      }
      packs[q] = L;
    }
    __syncthreads();
    #pragma unroll
    for (int q = 0; q < 4; q++) tile[p + 8*q][rloc] = packs[q];
    __syncthreads();
    int ckk = t >> 3;
    int r4  = (t & 7) * 4;
    size_t base = (size_t)(cp*32 + ckk) * NEPAD + brow + r4;
    *(uint4*)(levq + base) = make_uint4(tile[ckk][r4], tile[ckk][r4+1],
                                        tile[ckk][r4+2], tile[ckk][r4+3]);
  }

  unsigned long long c = cnt;
  c += __shfl_xor(c, 1);
  c += __shfl_xor(c, 2);
  c += __shfl_xor(c, 4);
  if (p == 0 && row < NEPAD){
    if (active){
      inv[row*8 + 0] = 0.f; inv[row*8 + 6] = 0.f; inv[row*8 + 7] = 0.f;
      #pragma unroll
      for (int r = 1; r <= 5; r++){
        uint32_t cc = (uint32_t)((c >> (12*(r-1))) & 0xFFFull);
        inv[row*8 + r] = cc ? 1.0f/(float)cc : 0.f;
      }
    } else {
      #pragma unroll
      for (int i = 0; i < 8; i++) inv[row*8 + i] = 0.f;
    }
  }

  int f0i = p * 16;
  if (active){
    union { uint16_t u[16]; uint4 q[2]; } ub;
    #pragma unroll
    for (int j = 0; j < 4; j++){
      float4 a = *(const float4*)(xe + (size_t)row*128 + f0i + j*4);
      ub.u[j*4+0]=f2bf(a.x); ub.u[j*4+1]=f2bf(a.y); ub.u[j*4+2]=f2bf(a.z); ub.u[j*4+3]=f2bf(a.w);
    }
    *(uint4*)(xebf + (size_t)row*128 + f0i)     = ub.q[0];
    *(uint4*)(xebf + (size_t)row*128 + f0i + 8) = ub.q[1];
  } else if (row < NEPAD){
    uint4 z = make_uint4(0,0,0,0);
    *(uint4*)(xebf + (size_t)row*128 + f0i)     = z;
    *(uint4*)(xebf + (size_t)row*128 + f0i + 8) = z;
  }
}

// ---- small GEMM [2048x128]@[128x128]; y=0: m1 (bias+relu); y>0: z1 pack ----
__global__ __launch_bounds__(256) void k_gemm(
    const float* __restrict__ Af, const uint16_t* __restrict__ Bm,
    const uint16_t* __restrict__ Bz, const float* __restrict__ bias,
    uint16_t* __restrict__ m1out, uint16_t* __restrict__ zpk){
  int tid = threadIdx.x;
  int lane = tid & 63, wid = tid >> 6;
  int l31 = lane & 31, g = lane >> 5;
  int by = blockIdx.y;
  bool m1path = (by == 0);
  int r = by - 1;
  const uint16_t* B = m1path ? Bm : (Bz + (size_t)r*16384);
  int arow = blockIdx.x*128 + wid*32 + l31;

  f16f acc[4];
  #pragma unroll
  for (int n = 0; n < 4; n++)
    #pragma unroll
    for (int i = 0; i < 16; i++) acc[n][i] = 0.f;

  #pragma unroll
  for (int ksI = 0; ksI < 8; ksI++){
    int k0 = ksI*16 + g*8;
    const float* ap = Af + (size_t)arow*128 + k0;
    float4 f0 = *(const float4*)ap;
    float4 f1 = *(const float4*)(ap + 4);
    union { uint16_t u[8]; bf8_t v; } ua;
    ua.u[0]=f2bf(f0.x); ua.u[1]=f2bf(f0.y); ua.u[2]=f2bf(f0.z); ua.u[3]=f2bf(f0.w);
    ua.u[4]=f2bf(f1.x); ua.u[5]=f2bf(f1.y); ua.u[6]=f2bf(f1.z); ua.u[7]=f2bf(f1.w);
    #pragma unroll
    for (int n = 0; n < 4; n++){
      bf8_t b = *(const bf8_t*)(B + (size_t)(n*32 + l31)*128 + k0);
      acc[n] = mfma32(ua.v, b, acc[n]);
    }
  }
  #pragma unroll
  for (int n = 0; n < 4; n++){
    int colg = n*32 + l31;
    float bv = m1path ? bias[colg] : 0.f;
    #pragma unroll
    for (int v = 0; v < 16; v++){
      int rowl = (v&3) + 8*(v>>2) + 4*g;
      int rg = blockIdx.x*128 + wid*32 + rowl;   // mole index j
      float val = acc[n][v];
      if (m1path){
        m1out[(size_t)rg*128 + colg] = f2bf(fmaxf(val + bv, 0.f));
      } else {
        int pos = ((rg & 1) << 2) | ((rg & 7) >> 1);
        zpk[(size_t)(r*256 + (rg>>3))*1024 + colg*8 + pos] = f2bf(val);
      }
    }
  }
}

// ---- masked RGCN conv: BM=128, 4 waves x 32 rows x full-N; Z dbuf in LDS ----
template<int NSLAB, bool FUSE>
__global__ __launch_bounds__(256, 3) void k_conv(
    const uint32_t* __restrict__ levq, const float* __restrict__ inv,
    const uint16_t* __restrict__ zpk, const uint16_t* __restrict__ aroot,
    const uint16_t* __restrict__ rt,
    const uint16_t* __restrict__ gA, const uint16_t* __restrict__ gB,
    uint16_t* __restrict__ gOut,
    uint16_t* __restrict__ p16, float* __restrict__ p32){
  int tid = threadIdx.x;
  int lane = tid & 63, wid = tid >> 6;     // 4 waves
  int l31 = lane & 31, g = lane >> 5;

  if (FUSE && blockIdx.x >= MB128){
    // ---- fused z2 gemm: 80 blocks x 128 rows: z2[r] = pack(m1 @ W2[r]) ----
    int b = blockIdx.y*10 + (blockIdx.x - MB128);   // 0..79
    int r = b >> 4;                                  // 0..4
    int rowb = (b & 15)*128 + wid*32;
    int arow = rowb + l31;
    const uint16_t* B = gB + (size_t)r*16384;
    f16f acc[4];
    #pragma unroll
    for (int n = 0; n < 4; n++)
      #pragma unroll
      for (int i = 0; i < 16; i++) acc[n][i] = 0.f;
    #pragma unroll
    for (int ksI = 0; ksI < 8; ksI++){
      int k0 = ksI*16 + g*8;
      bf8_t a = *(const bf8_t*)(gA + (size_t)arow*128 + k0);
      #pragma unroll
      for (int n = 0; n < 4; n++){
        bf8_t bb = *(const bf8_t*)(B + (size_t)(n*32 + l31)*128 + k0);
        acc[n] = mfma32(a, bb, acc[n]);
      }
    }
    #pragma unroll
    for (int n = 0; n < 4; n++){
      int colg = n*32 + l31;
      #pragma unroll
      for (int v = 0; v < 16; v++){
        int rowl = (v&3) + 8*(v>>2) + 4*g;
        int rg = rowb + rowl;
        int pos = ((rg & 1) << 2) | ((rg & 7) >> 1);
        gOut[(size_t)(r*256 + (rg>>3))*1024 + colg*8 + pos] = f2bf(acc[n][v]);
      }
    }
    return;
  }

  // ---- conv part ----
  int brow = blockIdx.x*128;
  int ks = blockIdx.y;                      // 0..7
  int kc0 = ks*32;                          // 32 8-k chunks per ks
  int row = brow + wid*32 + l31;            // this wave's 32 rows

  __shared__ uint16_t stage[2][10240];      // [(r*2+pc)*1024 + d*8 + pos]

  uint32_t tlo[5], thi[5];
  #pragma unroll
  for (int r = 1; r <= 5; r++){
    uint32_t bits = (uint32_t)f2bf(inv[(size_t)row*8 + r]);
    int sh = 8*((r+1)&3);
    tlo[r-1] = (bits & 0xFFu) << sh;
    thi[r-1] = (bits >> 8)    << sh;
  }

  f16f acc[4];
  #pragma unroll
  for (int n = 0; n < 4; n++)
    #pragma unroll
    for (int i = 0; i < 16; i++) acc[n][i] = 0.f;

  // prologue: stage kk=0 (5 x dwordx4 per thread = 20 KB/block)
  // linear uint4 index idx = j*256+tid: r = idx>>8, pc = (idx>>7)&1, q = idx&127
  uint4 sreg[5];
  #pragma unroll
  for (int j = 0; j < 5; j++){
    int idx = j*256 + tid;
    sreg[j] = *(const uint4*)(zpk + (size_t)((idx>>8)*256 + kc0 + ((idx>>7)&1))*1024
                                   + (idx & 127)*8);
  }
  #pragma unroll
  for (int j = 0; j < 5; j++)
    *(uint4*)(&stage[0][(j*256 + tid)*8]) = sreg[j];

  uint32_t Lc = levq[(size_t)(kc0 + g)*NEPAD + row];
  __syncthreads();

  int buf = 0;
  for (int kk = 0; kk < 16; kk++){
    uint32_t Ln;
    if (kk < 15){
      int ktn = kc0 + (kk+1)*2;
      #pragma unroll
      for (int j = 0; j < 5; j++){
        int idx = j*256 + tid;
        sreg[j] = *(const uint4*)(zpk + (size_t)((idx>>8)*256 + ktn + ((idx>>7)&1))*1024
                                       + (idx & 127)*8);
      }
      Ln = levq[(size_t)(ktn + g)*NEPAD + row];
    }
    uint32_t sx = Lc & 0x0F0F0F0Fu, sy = (Lc >> 4) & 0x0F0F0F0Fu;
    const uint16_t* sb = &stage[buf][g*1024 + l31*8];
    #pragma unroll
    for (int r = 1; r <= 5; r++){
      bf8_t bn0 = *(const bf8_t*)(sb + (r-1)*2048);
      bf8_t bn1 = *(const bf8_t*)(sb + (r-1)*2048 + 256);
      bf8_t bn2 = *(const bf8_t*)(sb + (r-1)*2048 + 512);
      bf8_t bn3 = *(const bf8_t*)(sb + (r-1)*2048 + 768);
      uint32_t TL = tlo[r-1], TH = thi[r-1];
      uint32_t pl, ph, ql, qh;
      if (r < 3){   // table byte at index 2..3 -> low pool (src1)
        pl = __builtin_amdgcn_perm(0u, TL, sx);
        ph = __builtin_amdgcn_perm(0u, TH, sx);
        ql = __builtin_amdgcn_perm(0u, TL, sy);
        qh = __builtin_amdgcn_perm(0u, TH, sy);
      } else {      // table byte at index 4..6 -> high pool (src0)
        pl = __builtin_amdgcn_perm(TL, 0u, sx);
        ph = __builtin_amdgcn_perm(TH, 0u, sx);
        ql = __builtin_amdgcn_perm(TL, 0u, sy);
        qh = __builtin_amdgcn_perm(TH, 0u, sy);
      }
      union { uint32_t u[4]; bf8_t v; } A;
      A.u[0] = __builtin_amdgcn_perm(ph, pl, 0x05010400u);
      A.u[1] = __builtin_amdgcn_perm(ph, pl, 0x07030602u);
      A.u[2] = __builtin_amdgcn_perm(qh, ql, 0x05010400u);
      A.u[3] = __builtin_amdgcn_perm(qh, ql, 0x07030602u);
      acc[0] = mfma32(A.v, bn0, acc[0]);
      acc[1] = mfma32(A.v, bn1, acc[1]);
      acc[2] = mfma32(A.v, bn2, acc[2]);
      acc[3] = mfma32(A.v, bn3, acc[3]);
    }
    if (kk < 15){
      #pragma unroll
      for (int j = 0; j < 5; j++)
        *(uint4*)(&stage[buf^1][(j*256 + tid)*8]) = sreg[j];
      __syncthreads();
      buf ^= 1;
      Lc = Ln;
    }
  }

  {  // root-matmul k-chunk ks (16 of 128) — exactly balanced over ks 0..7
    int k0 = ks*16 + g*8;
    bf8_t a = *(const bf8_t*)(aroot + (size_t)row*128 + k0);
    #pragma unroll
    for (int nt = 0; nt < 4; nt++){
      bf8_t rb = *(const bf8_t*)(rt + (size_t)(nt*32 + l31)*128 + k0);
      acc[nt] = mfma32(a, rb, acc[nt]);
    }
  }

  if (NSLAB == 8){
    uint16_t* dst = p16 + (size_t)ks*NEPAD*128;
    #pragma unroll
    for (int nt = 0; nt < 4; nt++){
      int colg = nt*32 + l31;
      #pragma unroll
      for (int v = 0; v < 16; v++){
        int rowl = (v&3) + 8*(v>>2) + 4*g;
        dst[(size_t)(brow + wid*32 + rowl)*128 + colg] = f2bf(acc[nt][v]);
      }
    }
  } else {
    #pragma unroll
    for (int nt = 0; nt < 4; nt++){
      int colg = nt*32 + l31;
      #pragma unroll
      for (int v = 0; v < 16; v++){
        int rowl = (v&3) + 8*(v>>2) + 4*g;
        unsafeAtomicAdd(&p32[(size_t)(brow + wid*32 + rowl)*128 + colg], acc[nt][v]);
      }
    }
  }
}

// ---- reduce 8 bf16 slabs (or 1 f32 slab) + bias; C1: relu->bf16, else f32 ----
template<bool C1, bool S16>
__global__ __launch_bounds__(256) void k_red(
    const uint16_t* __restrict__ p16, const float* __restrict__ p32,
    const float* __restrict__ bias, uint16_t* __restrict__ e1bf,
    float* __restrict__ out){
  size_t idx8 = ((size_t)blockIdx.x*256 + threadIdx.x) * 8;   // < NEPAD*128
  int col = (int)(idx8 & 127);
  float s[8];
  #pragma unroll
  for (int j = 0; j < 8; j++) s[j] = bias[col + j];
  if (S16){
    #pragma unroll
    for (int sl = 0; sl < 8; sl++){
      union { uint4 q; uint16_t h[8]; } u;
      u.q = *(const uint4*)(p16 + (size_t)sl*NEPAD*128 + idx8);
      #pragma unroll
      for (int j = 0; j < 8; j++) s[j] += __uint_as_float(((uint32_t)u.h[j]) << 16);
    }
  } else {
    #pragma unroll
    for (int j = 0; j < 8; j += 4){
      float4 v = *(const float4*)(p32 + idx8 + j);
      s[j] += v.x; s[j+1] += v.y; s[j+2] += v.z; s[j+3] += v.w;
    }
  }
  if (C1){
    union { uint16_t u[8]; uint4 q; } ub;
    #pragma unroll
    for (int j = 0; j < 8; j++) ub.u[j] = f2bf(fmaxf(s[j], 0.f));
    *(uint4*)(e1bf + idx8) = ub.q;
  } else {
    if (idx8 < (size_t)NE*128){
      *(float4*)(out + idx8)     = make_float4(s[0], s[1], s[2], s[3]);
      *(float4*)(out + idx8 + 4) = make_float4(s[4], s[5], s[6], s[7]);
    }
  }
}

extern "C" void kernel_launch(void* const* d_in, const int* in_sizes, int n_in,
                              void* d_out, int out_size, void* d_ws, size_t ws_size,
                              hipStream_t stream){
  const float* xe  = (const float*)d_in[0];
  const float* xm  = (const float*)d_in[1];
  const float* w   = (const float*)d_in[2];
  const float* W1  = (const float*)d_in[3];
  const float* r1  = (const float*)d_in[4];
  const float* b1  = (const float*)d_in[5];
  const float* W2  = (const float*)d_in[6];
  const float* r2  = (const float*)d_in[7];
  const float* b2  = (const float*)d_in[8];
  float* out = (float*)d_out;
  char* ws = (char*)d_ws;

  constexpr size_t OFF_INV  = 0;                                   // NEPAD*8*4
  constexpr size_t OFF_XEBF = OFF_INV  + (size_t)NEPAD*8*4;        // NEPAD*128*2 (also e1bf)
  constexpr size_t OFF_M1   = OFF_XEBF + (size_t)NEPAD*128*2;      // NM*128*2
  constexpr size_t OFF_Z1   = OFF_M1   + (size_t)NM*128*2;         // 5*NM*128*2
  constexpr size_t OFF_Z2   = OFF_Z1   + (size_t)5*NM*128*2;       // 5*NM*128*2
  constexpr size_t OFF_R1T  = OFF_Z2   + (size_t)5*NM*128*2;
  constexpr size_t OFF_R2T  = OFF_R1T  + 128*128*2;
  constexpr size_t OFF_W1T  = OFF_R2T  + 128*128*2;
  constexpr size_t OFF_W2T  = OFF_W1T  + (size_t)5*128*128*2;
  constexpr size_t OFF_LEVQ = OFF_W2T  + (size_t)5*128*128*2;      // 256*NEPAD*4 (~10.4MB)
  constexpr size_t OFF_PART = OFF_LEVQ + (size_t)256*NEPAD*4;
  constexpr size_t SLAB16   = (size_t)NEPAD*128*2;                 // 2.59 MB bf16 slab
  constexpr size_t NEED_A   = OFF_PART + 8*SLAB16;                 // ~42 MB
  constexpr size_t SLABF    = (size_t)NEPAD*128*4;                 // f32 fallback slab

  float*    inv  = (float*)   (ws + OFF_INV);
  uint16_t* xebf = (uint16_t*)(ws + OFF_XEBF);
  uint16_t* m1   = (uint16_t*)(ws + OFF_M1);
  uint16_t* z1   = (uint16_t*)(ws + OFF_Z1);
  uint16_t* z2   = (uint16_t*)(ws + OFF_Z2);
  uint16_t* r1t  = (uint16_t*)(ws + OFF_R1T);
  uint16_t* r2t  = (uint16_t*)(ws + OFF_R2T);
  uint16_t* w1t  = (uint16_t*)(ws + OFF_W1T);
  uint16_t* w2t  = (uint16_t*)(ws + OFF_W2T);
  uint32_t* levq = (uint32_t*)(ws + OFF_LEVQ);
  uint16_t* p16  = (uint16_t*)(ws + OFF_PART);
  float*    p32  = (float*)   (ws + OFF_PART);

  bool tierA = (ws_size >= NEED_A);

  // prep (48 blocks) + lev (316 blocks)
  hipLaunchKernelGGL(k_init, dim3(48 + NEPAD/32), dim3(256), 0, stream,
                     r1, r2, W1, W2, r1t, r2t, w1t, w2t,
                     w, xe, levq, inv, xebf);
  // y=0: m1 = relu(xm@root1+b1); y=1..5: z1[y-1] = pack(xm@W1[y-1])
  hipLaunchKernelGGL(k_gemm, dim3(16,6), dim3(256), 0, stream,
                     xm, r1t, w1t, b1, m1, z1);
  if (tierA){
    // conv1 partials + fused z2 gemm
    hipLaunchKernelGGL((k_conv<8,true>), dim3(MB128 + 10, KSPLIT), dim3(256), 0, stream,
                       levq, inv, z1, xebf, r1t, m1, w2t, z2, p16, (float*)nullptr);
    hipLaunchKernelGGL((k_red<true,true>), dim3(NEPAD*128/2048), dim3(256), 0, stream,
                       p16, (const float*)nullptr, b1, xebf, (float*)nullptr);
    hipLaunchKernelGGL((k_conv<8,false>), dim3(MB128, KSPLIT), dim3(256), 0, stream,
                       levq, inv, z2, xebf, r2t,
                       (const uint16_t*)nullptr, (const uint16_t*)nullptr,
                       (uint16_t*)nullptr, p16, (float*)nullptr);
    hipLaunchKernelGGL((k_red<false,true>), dim3(NEPAD*128/2048), dim3(256), 0, stream,
                       p16, (const float*)nullptr, b2, (uint16_t*)nullptr, out);
  } else {
    hipMemsetAsync(p32, 0, SLABF, stream);
    hipLaunchKernelGGL((k_conv<1,true>), dim3(MB128 + 10, KSPLIT), dim3(256), 0, stream,
                       levq, inv, z1, xebf, r1t, m1, w2t, z2,
                       (uint16_t*)nullptr, p32);
    hipLaunchKernelGGL((k_red<true,false>), dim3(NEPAD*128/2048), dim3(256), 0, stream,
                       (const uint16_t*)nullptr, p32, b1, xebf, (float*)nullptr);
    hipMemsetAsync(p32, 0, SLABF, stream);
    hipLaunchKernelGGL((k_conv<1,false>), dim3(MB128, KSPLIT), dim3(256), 0, stream,
                       levq, inv, z2, xebf, r2t,
                       (const uint16_t*)nullptr, (const uint16_t*)nullptr,
                       (uint16_t*)nullptr, (uint16_t*)nullptr, p32);
    hipLaunchKernelGGL((k_red<false,false>), dim3(NEPAD*128/2048), dim3(256), 0, stream,
                       (const uint16_t*)nullptr, p32, b2, (uint16_t*)nullptr, out);
  }
}